// Round 13
// baseline (437.639 us; speedup 1.0000x reference)
//
#include <hip/hip_runtime.h>
#include <stdint.h>

#define QL 2048
#define NHEAD 16
#define DHEAD 64
#define DMODEL 1024
#define DINNER 4096

typedef __attribute__((ext_vector_type(8))) short bf16x8;
typedef __attribute__((ext_vector_type(4))) float f32x4;

template <bool V>
struct BoolC { static constexpr bool value = V; };

__device__ __forceinline__ ushort f2bf(float f) {
  uint32_t u = __float_as_uint(f);
  u = (u + 0x7fffu + ((u >> 16) & 1u)) >> 16;
  return (ushort)u;
}
__device__ __forceinline__ float bf2f(ushort u) {
  return __uint_as_float(((uint32_t)u) << 16);
}

__device__ __forceinline__ void gload_lds16(const void* g, void* l) {
  auto gp = reinterpret_cast<const uint32_t __attribute__((address_space(1)))*>(
      reinterpret_cast<uintptr_t>(g));
  auto lp = reinterpret_cast<uint32_t __attribute__((address_space(3)))*>(
      (uint32_t)reinterpret_cast<uintptr_t>(l));
  __builtin_amdgcn_global_load_lds(gp, lp, 16, 0, 0);
}

// softmax scale folded into Q at projection: 0.125 * log2(e)
#define QSCALE 0.18033688011112042f

// ---------------- fp32 -> bf16 conversion (4 critical-path buffers) ----------
struct CvtArgs {
  const float* src[4];
  ushort* dst[4];
  int end[4];  // cumulative float4 counts
};

__global__ __launch_bounds__(256) void cvt_all_k(CvtArgs a, int total4) {
  for (int i = blockIdx.x * 256 + threadIdx.x; i < total4; i += gridDim.x * 256) {
    int seg = 0;
#pragma unroll
    for (int s = 0; s < 3; s++)
      if (i >= a.end[s]) seg = s + 1;
    int base = seg ? a.end[seg - 1] : 0;
    int j = i - base;
    float4 v = ((const float4*)a.src[seg])[j];
    ushort4 u;
    u.x = f2bf(v.x); u.y = f2bf(v.y); u.z = f2bf(v.z); u.w = f2bf(v.w);
    ((ushort4*)a.dst[seg])[j] = u;
  }
}

// ---- fat dispatch #1: QKV(768 blocks) + rk(512) + deferred cvt(512) --------
struct Cvt3 {
  const float* src[3];
  ushort* dst[3];
  int end[3];
};

__global__ __launch_bounds__(256) void fat_qkv_rk_cvt(
    const ushort* __restrict__ xb, const ushort* __restrict__ qkvw,
    const ushort* __restrict__ rb, const ushort* __restrict__ rnetw,
    ushort* __restrict__ qw, ushort* __restrict__ qr, ushort* __restrict__ kbuf,
    ushort* __restrict__ vt, ushort* __restrict__ rkout,
    const float* __restrict__ rwb, const float* __restrict__ rrb,
    Cvt3 cv, int cvt_total4) {
  __shared__ char smem[32768];
  const int bid = blockIdx.x;
  const int t = threadIdx.x;
  const int lane = t & 63, wv = t >> 6;
  const int wr = wv >> 1, wc = wv & 1;
  const int rif = lane & 15;
  const int kb = (lane >> 4) * 16;
  const int arow = t >> 2;
  const int acol = (t & 3) * 16;
  const int rbase = (lane >> 4) * 4;

  if (bid < 768) {
    // ---------- QKV: C[4096,3072] = xb × qkvw^T, 128² tile, 2-phase ----------
    const int bx = bid % 24, by = bid / 24;
    const int m0 = by * 128, n0 = bx * 128;
    const int K = 1024;
    const char* Ab = (const char*)xb;
    const char* Bb = (const char*)qkvw;

    f32x4 acc[4][4] = {};
    auto stage = [&](int b, int k0) {
      char* As = smem + b * 8192;
      char* Bs = smem + 16384 + b * 8192;
      size_t abase = ((size_t)(m0 + arow) * K + k0) * 2 + acol;
      gload_lds16(Ab + abase, As + t * 16);
      gload_lds16(Ab + abase + (size_t)64 * K * 2, As + t * 16 + 4096);
      size_t bbase = ((size_t)(n0 + arow) * K + k0) * 2 + acol;
      gload_lds16(Bb + bbase, Bs + t * 16);
      gload_lds16(Bb + bbase + (size_t)64 * K * 2, Bs + t * 16 + 4096);
    };

    stage(0, 0);
    asm volatile("s_waitcnt vmcnt(0)" ::: "memory");
    __builtin_amdgcn_s_barrier();
    __builtin_amdgcn_sched_barrier(0);

    int cur = 0;
#pragma unroll 1
    for (int k0 = 0; k0 < K; k0 += 32) {
      if (k0 + 32 < K) stage(cur ^ 1, k0 + 32);
      const char* As = smem + cur * 8192;
      const char* Bs = smem + 16384 + cur * 8192;
      bf16x8 af[4], bfr[4];
#pragma unroll
      for (int m = 0; m < 4; m++)
        af[m] = *(const bf16x8*)(As + (wr * 64 + m * 16 + rif) * 64 + kb);
#pragma unroll
      for (int n = 0; n < 4; n++)
        bfr[n] = *(const bf16x8*)(Bs + (wc * 64 + n * 16 + rif) * 64 + kb);
      __builtin_amdgcn_s_setprio(1);
#pragma unroll
      for (int m = 0; m < 4; m++)
#pragma unroll
        for (int n = 0; n < 4; n++)
          acc[m][n] = __builtin_amdgcn_mfma_f32_16x16x32_bf16(af[m], bfr[n], acc[m][n], 0, 0, 0);
      __builtin_amdgcn_s_setprio(0);
      asm volatile("s_waitcnt vmcnt(0)" ::: "memory");
      __builtin_amdgcn_s_barrier();
      __builtin_amdgcn_sched_barrier(0);
      cur ^= 1;
    }

#pragma unroll
    for (int m = 0; m < 4; m++) {
#pragma unroll
      for (int n = 0; n < 4; n++) {
#pragma unroll
        for (int reg = 0; reg < 4; reg++) {
          int gr = m0 + wr * 64 + m * 16 + rbase + reg;
          int gc = n0 + wc * 64 + n * 16 + (lane & 15);
          float v = acc[m][n][reg];
          int which = gc >> 10, hh = gc & 1023;
          int hn = hh >> 6, hd = hh & 63;
          int qi = gr >> 1, qb = gr & 1;
          size_t off = ((size_t)(qb * NHEAD + hn) * QL + qi) * 64 + hd;
          if (which == 0) {
            qw[off] = f2bf((v + rwb[hh]) * QSCALE);
            qr[off] = f2bf((v + rrb[hh]) * QSCALE);
          } else if (which == 1) {
            kbuf[off] = f2bf(v);
          } else {
            vt[((size_t)(qb * NHEAD + hn) * 64 + hd) * QL + qi] = f2bf(v);
          }
        }
      }
    }
  } else if (bid < 1280) {
    // ---------- rk: rkout = rb[2048,1024] × rnetw^T, 64² tile, 2-phase -------
    const int b = bid - 768;
    const int bx = b % 16, by = b / 16;
    const int m0 = by * 64, n0 = bx * 64;
    const int K = 1024;
    const char* Ab = (const char*)rb;
    const char* Bb = (const char*)rnetw;

    f32x4 acc[2][2] = {};
    auto stage = [&](int bb, int k0) {
      char* As = smem + bb * 4096;
      char* Bs = smem + 8192 + bb * 4096;
      size_t abase = ((size_t)(m0 + arow) * K + k0) * 2 + acol;
      gload_lds16(Ab + abase, As + t * 16);
      size_t bbase = ((size_t)(n0 + arow) * K + k0) * 2 + acol;
      gload_lds16(Bb + bbase, Bs + t * 16);
    };

    stage(0, 0);
    asm volatile("s_waitcnt vmcnt(0)" ::: "memory");
    __builtin_amdgcn_s_barrier();
    __builtin_amdgcn_sched_barrier(0);

    int cur = 0;
#pragma unroll 1
    for (int k0 = 0; k0 < K; k0 += 32) {
      if (k0 + 32 < K) stage(cur ^ 1, k0 + 32);
      const char* As = smem + cur * 4096;
      const char* Bs = smem + 8192 + cur * 4096;
      bf16x8 af[2], bfr[2];
#pragma unroll
      for (int m = 0; m < 2; m++)
        af[m] = *(const bf16x8*)(As + (wr * 32 + m * 16 + rif) * 64 + kb);
#pragma unroll
      for (int n = 0; n < 2; n++)
        bfr[n] = *(const bf16x8*)(Bs + (wc * 32 + n * 16 + rif) * 64 + kb);
      __builtin_amdgcn_s_setprio(1);
#pragma unroll
      for (int m = 0; m < 2; m++)
#pragma unroll
        for (int n = 0; n < 2; n++)
          acc[m][n] = __builtin_amdgcn_mfma_f32_16x16x32_bf16(af[m], bfr[n], acc[m][n], 0, 0, 0);
      __builtin_amdgcn_s_setprio(0);
      asm volatile("s_waitcnt vmcnt(0)" ::: "memory");
      __builtin_amdgcn_s_barrier();
      __builtin_amdgcn_sched_barrier(0);
      cur ^= 1;
    }

#pragma unroll
    for (int m = 0; m < 2; m++) {
#pragma unroll
      for (int n = 0; n < 2; n++) {
#pragma unroll
        for (int reg = 0; reg < 4; reg++) {
          int gr = m0 + wr * 32 + m * 16 + rbase + reg;
          int gc = n0 + wc * 32 + n * 16 + (lane & 15);
          int hn = gc >> 6, hd = gc & 63;
          rkout[((size_t)hn * QL + gr) * 64 + hd] = f2bf(acc[m][n][reg]);
        }
      }
    }
  } else {
    // ---------- deferred cvt of o_w, w1, w2 (not needed until after flash) ---
    for (int i = (bid - 1280) * 256 + t; i < cvt_total4; i += 512 * 256) {
      int seg = 0;
#pragma unroll
      for (int s = 0; s < 2; s++)
        if (i >= cv.end[s]) seg = s + 1;
      int base = seg ? cv.end[seg - 1] : 0;
      int j = i - base;
      float4 v = ((const float4*)cv.src[seg])[j];
      ushort4 u;
      u.x = f2bf(v.x); u.y = f2bf(v.y); u.z = f2bf(v.z); u.w = f2bf(v.w);
      ((ushort4*)cv.dst[seg])[j] = u;
    }
  }
}

// ---------------- FFN1 GEMM (R8-proven 2-phase, bias+relu+bf16) -------------
__global__ __launch_bounds__(256) void gemm_ffn1(
    const ushort* __restrict__ A, const ushort* __restrict__ B, int M, int N, int K,
    ushort* __restrict__ Cb, const float* __restrict__ bias) {
  __shared__ ushort As[2][128 * 32];
  __shared__ ushort Bs[2][128 * 32];
  const int t = threadIdx.x;
  const int lane = t & 63, wv = t >> 6;
  const int wr = wv >> 1, wc = wv & 1;
  const int m0 = blockIdx.y * 128, n0 = blockIdx.x * 128;
  const int rif = lane & 15;
  const int kb = (lane >> 4) * 16;

  f32x4 acc[4][4] = {};
  const char* Ab = (const char*)A;
  const char* Bb = (const char*)B;
  const int arow = t >> 2;
  const int acol = (t & 3) * 16;

  auto stage = [&](int b, int k0) {
    size_t abase = ((size_t)(m0 + arow) * K + k0) * 2 + acol;
    gload_lds16(Ab + abase, (char*)As[b] + t * 16);
    gload_lds16(Ab + abase + (size_t)64 * K * 2, (char*)As[b] + t * 16 + 4096);
    size_t bbase = ((size_t)(n0 + arow) * K + k0) * 2 + acol;
    gload_lds16(Bb + bbase, (char*)Bs[b] + t * 16);
    gload_lds16(Bb + bbase + (size_t)64 * K * 2, (char*)Bs[b] + t * 16 + 4096);
  };

  stage(0, 0);
  asm volatile("s_waitcnt vmcnt(0)" ::: "memory");
  __builtin_amdgcn_s_barrier();
  __builtin_amdgcn_sched_barrier(0);

  int cur = 0;
#pragma unroll 1
  for (int k0 = 0; k0 < K; k0 += 32) {
    if (k0 + 32 < K) stage(cur ^ 1, k0 + 32);
    bf16x8 af[4], bfr[4];
#pragma unroll
    for (int m = 0; m < 4; m++)
      af[m] = *(const bf16x8*)((const char*)As[cur] + (wr * 64 + m * 16 + rif) * 64 + kb);
#pragma unroll
    for (int n = 0; n < 4; n++)
      bfr[n] = *(const bf16x8*)((const char*)Bs[cur] + (wc * 64 + n * 16 + rif) * 64 + kb);
    __builtin_amdgcn_s_setprio(1);
#pragma unroll
    for (int m = 0; m < 4; m++)
#pragma unroll
      for (int n = 0; n < 4; n++)
        acc[m][n] = __builtin_amdgcn_mfma_f32_16x16x32_bf16(af[m], bfr[n], acc[m][n], 0, 0, 0);
    __builtin_amdgcn_s_setprio(0);
    asm volatile("s_waitcnt vmcnt(0)" ::: "memory");
    __builtin_amdgcn_s_barrier();
    __builtin_amdgcn_sched_barrier(0);
    cur ^= 1;
  }

  const int rbase = (lane >> 4) * 4;
#pragma unroll
  for (int m = 0; m < 4; m++) {
#pragma unroll
    for (int n = 0; n < 4; n++) {
#pragma unroll
      for (int reg = 0; reg < 4; reg++) {
        int gr = m0 + wr * 64 + m * 16 + rbase + reg;
        int gc = n0 + wc * 64 + n * 16 + (lane & 15);
        Cb[(size_t)gr * N + gc] = f2bf(fmaxf(acc[m][n][reg] + bias[gc], 0.f));
      }
    }
  }
}

// ---- split-K BN=64 GEMM for N=1024 (o-proj, FFN2), bf16 partials ----------
template <int WITH_BIAS>
__global__ __launch_bounds__(256) void gemm_nt64sk(
    const ushort* __restrict__ A, const ushort* __restrict__ B, int M, int N, int Kfull,
    int Klen, ushort* __restrict__ Cb0, ushort* __restrict__ Cb1,
    const float* __restrict__ bias) {
  __shared__ ushort As[2][128 * 32];
  __shared__ ushort Bs[2][64 * 32];
  const int t = threadIdx.x;
  const int lane = t & 63, wv = t >> 6;
  const int wr = wv >> 1, wc = wv & 1;
  const int m0 = blockIdx.y * 128, n0 = blockIdx.x * 64;
  const int z = blockIdx.z;
  const int koff = z * Klen;
  ushort* Cb = z ? Cb1 : Cb0;
  const int rif = lane & 15;
  const int kb = (lane >> 4) * 16;

  f32x4 acc[4][2] = {};
  const char* Ab = (const char*)A;
  const char* Bb = (const char*)B;
  const int arow = t >> 2;
  const int acol = (t & 3) * 16;

  auto stage = [&](int b, int k0) {
    size_t abase = ((size_t)(m0 + arow) * Kfull + koff + k0) * 2 + acol;
    gload_lds16(Ab + abase, (char*)As[b] + t * 16);
    gload_lds16(Ab + abase + (size_t)64 * Kfull * 2, (char*)As[b] + t * 16 + 4096);
    size_t bbase = ((size_t)(n0 + arow) * Kfull + koff + k0) * 2 + acol;
    gload_lds16(Bb + bbase, (char*)Bs[b] + t * 16);
  };

  stage(0, 0);
  asm volatile("s_waitcnt vmcnt(0)" ::: "memory");
  __builtin_amdgcn_s_barrier();
  __builtin_amdgcn_sched_barrier(0);

  int cur = 0;
#pragma unroll 1
  for (int k0 = 0; k0 < Klen; k0 += 32) {
    if (k0 + 32 < Klen) stage(cur ^ 1, k0 + 32);
    bf16x8 af[4], bfr[2];
#pragma unroll
    for (int m = 0; m < 4; m++)
      af[m] = *(const bf16x8*)((const char*)As[cur] + (wr * 64 + m * 16 + rif) * 64 + kb);
#pragma unroll
    for (int n = 0; n < 2; n++)
      bfr[n] = *(const bf16x8*)((const char*)Bs[cur] + (wc * 32 + n * 16 + rif) * 64 + kb);
    __builtin_amdgcn_s_setprio(1);
#pragma unroll
    for (int m = 0; m < 4; m++)
#pragma unroll
      for (int n = 0; n < 2; n++)
        acc[m][n] = __builtin_amdgcn_mfma_f32_16x16x32_bf16(af[m], bfr[n], acc[m][n], 0, 0, 0);
    __builtin_amdgcn_s_setprio(0);
    asm volatile("s_waitcnt vmcnt(0)" ::: "memory");
    __builtin_amdgcn_s_barrier();
    __builtin_amdgcn_sched_barrier(0);
    cur ^= 1;
  }

  const int rbase = (lane >> 4) * 4;
#pragma unroll
  for (int m = 0; m < 4; m++) {
#pragma unroll
    for (int n = 0; n < 2; n++) {
#pragma unroll
      for (int reg = 0; reg < 4; reg++) {
        int gr = m0 + wr * 64 + m * 16 + rbase + reg;
        int gc = n0 + wc * 32 + n * 16 + (lane & 15);
        float v = acc[m][n][reg];
        if (WITH_BIAS && z == 0) v += bias[gc];
        Cb[(size_t)gr * N + gc] = f2bf(v);
      }
    }
  }
}

// ---------------- fused causal attention with TXL rel-shift ----------------
// 48KB LDS -> 3 blocks/CU: (a) R ring buffer (128-row window, stage only 64
// new rows/iter AFTER barrier#1 so recycled slots are provably idle — fixes
// R2's race), (b) P overlays K[cur] (dead after barrier#1, R4-proven).
// Grid (32,32) skew, heavy tiles dispatched first.
__global__ __launch_bounds__(256) void flash_attn(
    const ushort* __restrict__ Qw, const ushort* __restrict__ Qr,
    const ushort* __restrict__ Kb, const ushort* __restrict__ Vt,
    const ushort* __restrict__ Rk, ushort* __restrict__ out) {
  __shared__ ushort K_lds[2][64 * 64];  // K tile; K[cur] doubles as P after barrier#1
  __shared__ ushort V_lds[2][64 * 64];  // [d][j], swizzled
  __shared__ ushort R_ring[128 * 64];   // ring keyed by global row & 127, swizzled

  const int t = threadIdx.x;
  const int lane = t & 63, wv = t >> 6;
  const int bn = blockIdx.y;
  const int qb = bn >> 4, hn = bn & 15;
  const int c4 = lane & 15, g4 = lane >> 4;

  const int itile = 31 - (int)blockIdx.x;  // heavy tiles first
  const int i0 = itile * 64;
  const int iw = i0 + wv * 16;
  const int niter = itile + 1;

  const char* Qwb = (const char*)(Qw + (size_t)bn * QL * 64);
  const char* Qrb = (const char*)(Qr + (size_t)bn * QL * 64);
  const char* Kbb = (const char*)(Kb + (size_t)bn * QL * 64);
  const char* Vtb = (const char*)(Vt + (size_t)bn * 64 * QL);
  const char* Rkb = (const char*)(Rk + (size_t)hn * QL * 64);

  int addrs[4];
#pragma unroll
  for (int reg = 0; reg < 4; reg++) {
    int rr = g4 * 4 + reg;
    addrs[reg] = ((lane & 48) | ((c4 + 15 - rr) & 15)) << 2;
  }

  bf16x8 qwf[2], qrf[2];
#pragma unroll
  for (int kk = 0; kk < 2; kk++) {
    qwf[kk] = *(const bf16x8*)(Qwb + (size_t)(iw + c4) * 128 + kk * 64 + g4 * 16);
    qrf[kk] = *(const bf16x8*)(Qrb + (size_t)(iw + c4) * 128 + kk * 64 + g4 * 16);
  }

  f32x4 o_acc[4] = {};
  float m_run[4], l_run[4];
#pragma unroll
  for (int r = 0; r < 4; r++) { m_run[r] = -3.0e38f; l_run[r] = 0.f; }

  // stage K,V tile j0 into buffer b (linear dest, pre-swizzled source)
  auto stageKV = [&](int b, int j0) {
#pragma unroll
    for (int p = 0; p < 2; p++) {
      int o = t * 16 + p * 4096;
      int row = o >> 7, ch16 = ((((o & 127) >> 4) ^ (row & 7)) << 4);
      gload_lds16(Kbb + (size_t)(j0 + row) * 128 + ch16, (char*)K_lds[b] + o);
      gload_lds16(Vtb + (size_t)row * (QL * 2) + (size_t)j0 * 2 + ch16, (char*)V_lds[b] + o);
    }
  };

  // tile body. T0 = j0 - i0 + QL - 64 (multiple of 64). Ring slot = global row & 127.
  auto tile_body = [&](int j0, int cur, bool ring_next, auto mc) {
    constexpr bool MASKED = decltype(mc)::value;
    const int T0 = j0 - i0 + (QL - 64);
    const int ph0 = T0 & 127;
    f32x4 acc_s[4] = {};
    f32x4 acc_bd[5] = {};
    const int baseloc = 48 - wv * 16;
    __builtin_amdgcn_s_setprio(1);
#pragma unroll
    for (int kk = 0; kk < 2; kk++) {
      const int sw = (((kk * 4 + g4) ^ (c4 & 7)) << 4);
#pragma unroll
      for (int nf = 0; nf < 4; nf++) {
        bf16x8 bk = *(const bf16x8*)((const char*)K_lds[cur] + (nf * 16 + c4) * 128 + sw);
        acc_s[nf] = __builtin_amdgcn_mfma_f32_16x16x32_bf16(qwf[kk], bk, acc_s[nf], 0, 0, 0);
      }
#pragma unroll
      for (int tf = 0; tf < 5; tf++) {
        int oo = baseloc + tf * 16 + c4;            // local row, oo&7 == c4&7
        int phys = (ph0 + oo) & 127;                // ring slot
        bf16x8 br = *(const bf16x8*)((const char*)R_ring + phys * 128 + sw);
        acc_bd[tf] = __builtin_amdgcn_mfma_f32_16x16x32_bf16(qrf[kk], br, acc_bd[tf], 0, 0, 0);
      }
    }
    __builtin_amdgcn_s_setprio(0);

    // barrier #1: all waves done reading K[cur] and the R window
    __builtin_amdgcn_s_barrier();
    __builtin_amdgcn_sched_barrier(0);

    // ring-stage 64 new rows (T0+128 .. T0+191) for the NEXT iteration
    if (ring_next) {
#pragma unroll
      for (int p = 0; p < 2; p++) {
        int o = t * 16 + p * 4096;
        int r = o >> 7;                              // 0..63
        int T = T0 + 128 + r;
        int srow = T > QL - 1 ? QL - 1 : T;          // clamped rows feed masked cells only
        int phys = T & 127;                          // phys&7 == r&7
        int ch16 = ((((o & 127) >> 4) ^ (r & 7)) << 4);
        gload_lds16(Rkb + (size_t)srow * 128 + ch16, (char*)R_ring + phys * 128 + (o & 127));
      }
    }

    uint32_t pk[4][4];
#pragma unroll
    for (int nf = 0; nf < 4; nf++)
#pragma unroll
      for (int reg = 0; reg < 4; reg++)
        asm("v_cvt_pk_bf16_f32 %0, %1, %2"
            : "=v"(pk[nf][reg])
            : "v"(acc_bd[nf][reg]), "v"(acc_bd[nf + 1][reg]));

    float sv[4][4];
    float rowmax[4] = {-3.0e38f, -3.0e38f, -3.0e38f, -3.0e38f};
#pragma unroll
    for (int nf = 0; nf < 4; nf++) {
#pragma unroll
      for (int reg = 0; reg < 4; reg++) {
        int rr = g4 * 4 + reg;
        uint32_t pulled = (uint32_t)__builtin_amdgcn_ds_bpermute(addrs[reg], (int)pk[nf][reg]);
        uint32_t bits = (c4 > rr) ? (pulled & 0xffff0000u) : (pulled << 16);
        float v = acc_s[nf][reg] + __uint_as_float(bits);
        if (MASKED) {
          int jg = j0 + nf * 16 + c4;
          int ig = iw + rr;
          v = (jg <= ig) ? v : -3.0e38f;
        }
        sv[nf][reg] = v;
        rowmax[reg] = fmaxf(rowmax[reg], v);
      }
    }
#pragma unroll
    for (int reg = 0; reg < 4; reg++) {
      float rm = rowmax[reg];
      rm = fmaxf(rm, __shfl_xor(rm, 1));
      rm = fmaxf(rm, __shfl_xor(rm, 2));
      rm = fmaxf(rm, __shfl_xor(rm, 4));
      rm = fmaxf(rm, __shfl_xor(rm, 8));
      float mnew = fmaxf(m_run[reg], rm);
      float alpha = __builtin_amdgcn_exp2f(m_run[reg] - mnew);
      float rsum = 0.f;
#pragma unroll
      for (int nf = 0; nf < 4; nf++) {
        float p = __builtin_amdgcn_exp2f(sv[nf][reg] - mnew);
        sv[nf][reg] = p;
        rsum += p;
      }
      rsum += __shfl_xor(rsum, 1);
      rsum += __shfl_xor(rsum, 2);
      rsum += __shfl_xor(rsum, 4);
      rsum += __shfl_xor(rsum, 8);
      l_run[reg] = l_run[reg] * alpha + rsum;
      m_run[reg] = mnew;
#pragma unroll
      for (int df = 0; df < 4; df++) o_acc[df][reg] *= alpha;
    }

    // P -> K[cur] space (dead after barrier#1); per-wave 2KB slice
    {
      char* pb = (char*)K_lds[cur] + wv * 2048;
#pragma unroll
      for (int nf = 0; nf < 4; nf++)
#pragma unroll
        for (int reg = 0; reg < 4; reg++) {
          int row = g4 * 4 + reg, col = nf * 16 + c4;
          int byt = row * 128 + ((((col >> 3) ^ (row & 7))) << 4) + (col & 7) * 2;
          *(ushort*)(pb + byt) = f2bf(sv[nf][reg]);
        }
    }
    __builtin_amdgcn_s_setprio(1);
#pragma unroll
    for (int kk = 0; kk < 2; kk++) {
      const char* pb = (const char*)K_lds[cur] + wv * 2048;
      bf16x8 pa = *(const bf16x8*)(pb + c4 * 128 + (((kk * 4 + g4) ^ (c4 & 7)) << 4));
      const int sw = (((kk * 4 + g4) ^ (c4 & 7)) << 4);
#pragma unroll
      for (int df = 0; df < 4; df++) {
        bf16x8 bv = *(const bf16x8*)((const char*)V_lds[cur] + (df * 16 + c4) * 128 + sw);
        o_acc[df] = __builtin_amdgcn_mfma_f32_16x16x32_bf16(pa, bv, o_acc[df], 0, 0, 0);
      }
    }
    __builtin_amdgcn_s_setprio(0);
  };

  // prologue: K,V tile 0 + full 128-row R window (rows T0..T0+127, T0 = QL-64-i0)
  stageKV(0, 0);
  {
    const int T0 = QL - 64 - i0;
#pragma unroll
    for (int p = 0; p < 4; p++) {
      int o = t * 16 + p * 4096;
      int r = o >> 7;
      int T = T0 + r;
      int srow = T > QL - 1 ? QL - 1 : T;
      int phys = T & 127;
      int ch16 = ((((o & 127) >> 4) ^ (r & 7)) << 4);
      gload_lds16(Rkb + (size_t)srow * 128 + ch16, (char*)R_ring + phys * 128 + (o & 127));
    }
  }
  asm volatile("s_waitcnt vmcnt(0)" ::: "memory");
  __builtin_amdgcn_s_barrier();
  __builtin_amdgcn_sched_barrier(0);

  int cur = 0;
#pragma unroll 1
  for (int it = 0; it < niter - 1; ++it) {
    stageKV(cur ^ 1, (it + 1) * 64);
    tile_body(it * 64, cur, true, BoolC<false>{});
    asm volatile("s_waitcnt vmcnt(0)" ::: "memory");
    __builtin_amdgcn_s_barrier();
    __builtin_amdgcn_sched_barrier(0);
    cur ^= 1;
  }
  tile_body(i0, cur, false, BoolC<true>{});

#pragma unroll
  for (int reg = 0; reg < 4; reg++) {
    float inv = 1.0f / l_run[reg];
    int ig = iw + g4 * 4 + reg;
    size_t grow = (size_t)(ig * 2 + qb) * 1024 + hn * 64;
#pragma unroll
    for (int df = 0; df < 4; df++)
      out[grow + df * 16 + c4] = f2bf(o_acc[df][reg] * inv);
  }
}

// ---------------- residual + 2 bf16 partials + LayerNorm --------------------
template <bool WB>
__global__ __launch_bounds__(256) void ln_res3(
    const float* __restrict__ xa, const ushort* __restrict__ xb0,
    const ushort* __restrict__ xb1, const float* __restrict__ g,
    const float* __restrict__ bt, float* __restrict__ of, ushort* __restrict__ ob) {
  __shared__ float red[8];
  const int row = blockIdx.x;
  const int t = threadIdx.x;
  const int lane = t & 63, wv = t >> 6;
  const float4 a = *(const float4*)(xa + (size_t)row * 1024 + t * 4);
  const ushort4 c0 = *(const ushort4*)(xb0 + (size_t)row * 1024 + t * 4);
  const ushort4 c1 = *(const ushort4*)(xb1 + (size_t)row * 1024 + t * 4);
  float x[4] = {a.x + bf2f(c0.x) + bf2f(c1.x), a.y + bf2f(c0.y) + bf2f(c1.y),
                a.z + bf2f(c0.z) + bf2f(c1.z), a.w + bf2f(c0.w) + bf2f(c1.w)};
  float s = x[0] + x[1] + x[2] + x[3];
  for (int m = 1; m < 64; m <<= 1) s += __shfl_xor(s, m);
  if (lane == 0) red[wv] = s;
  __syncthreads();
  float mu = (red[0] + red[1] + red[2] + red[3]) * (1.f / 1024.f);
  float d[4];
  float ss = 0.f;
#pragma unroll
  for (int i = 0; i < 4; i++) { d[i] = x[i] - mu; ss += d[i] * d[i]; }
  for (int m = 1; m < 64; m <<= 1) ss += __shfl_xor(ss, m);
  if (lane == 0) red[4 + wv] = ss;
  __syncthreads();
  float var = (red[4] + red[5] + red[6] + red[7]) * (1.f / 1024.f);
  float rs = rsqrtf(var + 1e-5f);
  float4 gv = *(const float4*)(g + t * 4);
  float4 bv = *(const float4*)(bt + t * 4);
  float y[4] = {d[0] * rs * gv.x + bv.x, d[1] * rs * gv.y + bv.y,
                d[2] * rs * gv.z + bv.z, d[3] * rs * gv.w + bv.w};
  float4 yo = make_float4(y[0], y[1], y[2], y[3]);
  *(float4*)(of + (size_t)row * 1024 + t * 4) = yo;
  if (WB) {
    ushort4 u;
    u.x = f2bf(y[0]); u.y = f2bf(y[1]); u.z = f2bf(y[2]); u.w = f2bf(y[3]);
    *(ushort4*)(ob + (size_t)row * 1024 + t * 4) = u;
  }
}

// ---------------- host orchestration ----------------
extern "C" void kernel_launch(void* const* d_in, const int* in_sizes, int n_in,
                              void* d_out, int out_size, void* d_ws, size_t ws_size,
                              hipStream_t stream) {
  const float* dec_inp = (const float*)d_in[0];
  const float* r_in = (const float*)d_in[1];
  const float* rwb = (const float*)d_in[2];
  const float* rrb = (const float*)d_in[3];
  const float* qkv_w = (const float*)d_in[4];
  const float* rnet_w = (const float*)d_in[5];
  const float* o_w = (const float*)d_in[6];
  const float* ln_attn_g = (const float*)d_in[7];
  const float* ln_attn_b = (const float*)d_in[8];
  const float* w1 = (const float*)d_in[9];
  const float* b1 = (const float*)d_in[10];
  const float* w2 = (const float*)d_in[11];
  const float* b2 = (const float*)d_in[12];
  const float* ln_ff_g = (const float*)d_in[13];
  const float* ln_ff_b = (const float*)d_in[14];
  float* out = (float*)d_out;

  char* ws = (char*)d_ws;
  size_t off = 0;
  auto alloc = [&](size_t bytes) {
    char* p = ws + off;
    off += (bytes + 255) & ~(size_t)255;
    return p;
  };
  const int ROWS = QL * 2;
  ushort* qkvw_b = (ushort*)alloc((size_t)3072 * 1024 * 2);
  ushort* rnetw_b = (ushort*)alloc((size_t)1024 * 1024 * 2);
  ushort* ow_b = (ushort*)alloc((size_t)1024 * 1024 * 2);
  ushort* w1_b = (ushort*)alloc((size_t)4096 * 1024 * 2);
  ushort* w2_b = (ushort*)alloc((size_t)1024 * 4096 * 2);
  ushort* x_b = (ushort*)alloc((size_t)ROWS * 1024 * 2);
  ushort* r_b = (ushort*)alloc((size_t)QL * 1024 * 2);
  ushort* Qw = (ushort*)alloc((size_t)32 * QL * 64 * 2);
  ushort* Qr = (ushort*)alloc((size_t)32 * QL * 64 * 2);
  ushort* Kb = (ushort*)alloc((size_t)32 * QL * 64 * 2);
  ushort* Vt = (ushort*)alloc((size_t)32 * 64 * QL * 2);
  ushort* rk = (ushort*)alloc((size_t)16 * QL * 64 * 2);
  ushort* avec = (ushort*)alloc((size_t)ROWS * 1024 * 2);
  ushort* p0 = (ushort*)alloc((size_t)ROWS * 1024 * 2);
  ushort* p1 = (ushort*)alloc((size_t)ROWS * 1024 * 2);
  float* x1f = (float*)alloc((size_t)ROWS * 1024 * 4);
  ushort* x1b = (ushort*)alloc((size_t)ROWS * 1024 * 2);
  ushort* hidden = (ushort*)alloc((size_t)ROWS * 4096 * 2);
  ushort* q0 = (ushort*)alloc((size_t)ROWS * 1024 * 2);
  ushort* q1 = (ushort*)alloc((size_t)ROWS * 1024 * 2);

  // critical-path conversions: qkv_w, rnet_w, dec_inp, r
  CvtArgs ca;
  {
    int n4[4] = {3072 * 1024 / 4, 1024 * 1024 / 4, ROWS * 1024 / 4, QL * 1024 / 4};
    const float* srcs[4] = {qkv_w, rnet_w, dec_inp, r_in};
    ushort* dsts[4] = {qkvw_b, rnetw_b, x_b, r_b};
    int cum = 0;
    for (int i = 0; i < 4; i++) {
      ca.src[i] = srcs[i];
      ca.dst[i] = dsts[i];
      cum += n4[i];
      ca.end[i] = cum;
    }
    cvt_all_k<<<2048, 256, 0, stream>>>(ca, cum);
  }

  // fat dispatch: QKV proj + rk proj + deferred cvt of o_w/w1/w2
  Cvt3 cv;
  int cvt_total4;
  {
    int n4[3] = {1024 * 1024 / 4, 4096 * 1024 / 4, 1024 * 4096 / 4};
    const float* srcs[3] = {o_w, w1, w2};
    ushort* dsts[3] = {ow_b, w1_b, w2_b};
    int cum = 0;
    for (int i = 0; i < 3; i++) {
      cv.src[i] = srcs[i];
      cv.dst[i] = dsts[i];
      cum += n4[i];
      cv.end[i] = cum;
    }
    cvt_total4 = cum;
  }
  fat_qkv_rk_cvt<<<1792, 256, 0, stream>>>(x_b, qkvw_b, r_b, rnetw_b, Qw, Qr, Kb, Vt, rk,
                                           rwb, rrb, cv, cvt_total4);

  flash_attn<<<dim3(32, 32), 256, 0, stream>>>(Qw, Qr, Kb, Vt, rk, avec);
  // o-proj split-K=2 (K=512 each), bf16 partials p0/p1
  gemm_nt64sk<0><<<dim3(1024 / 64, ROWS / 128, 2), 256, 0, stream>>>(
      avec, ow_b, ROWS, 1024, 1024, 512, p0, p1, nullptr);
  ln_res3<true><<<ROWS, 256, 0, stream>>>(dec_inp, p0, p1, ln_attn_g, ln_attn_b, x1f, x1b);
  gemm_ffn1<<<dim3(4096 / 128, ROWS / 128), 256, 0, stream>>>(
      x1b, w1_b, ROWS, 4096, 1024, hidden, b1);
  // FFN2 split-K=2 (K=2048 each), bias folded into z==0 partial
  gemm_nt64sk<1><<<dim3(1024 / 64, ROWS / 128, 2), 256, 0, stream>>>(
      hidden, w2_b, ROWS, 1024, 4096, 2048, q0, q1, b2);
  ln_res3<false><<<ROWS, 256, 0, stream>>>(x1f, q0, q1, ln_ff_g, ln_ff_b, out, nullptr);
}

// Round 14
// 337.491 us; speedup vs baseline: 1.2967x; 1.2967x over previous
//
#include <hip/hip_runtime.h>
#include <stdint.h>

#define QL 2048
#define NHEAD 16
#define DHEAD 64
#define DMODEL 1024
#define DINNER 4096

typedef __attribute__((ext_vector_type(8))) short bf16x8;
typedef __attribute__((ext_vector_type(4))) float f32x4;

template <bool V>
struct BoolC { static constexpr bool value = V; };

__device__ __forceinline__ ushort f2bf(float f) {
  uint32_t u = __float_as_uint(f);
  u = (u + 0x7fffu + ((u >> 16) & 1u)) >> 16;
  return (ushort)u;
}
__device__ __forceinline__ float bf2f(ushort u) {
  return __uint_as_float(((uint32_t)u) << 16);
}

__device__ __forceinline__ void gload_lds16(const void* g, void* l) {
  auto gp = reinterpret_cast<const uint32_t __attribute__((address_space(1)))*>(
      reinterpret_cast<uintptr_t>(g));
  auto lp = reinterpret_cast<uint32_t __attribute__((address_space(3)))*>(
      (uint32_t)reinterpret_cast<uintptr_t>(l));
  __builtin_amdgcn_global_load_lds(gp, lp, 16, 0, 0);
}

// softmax scale folded into Q at projection: 0.125 * log2(e)
#define QSCALE 0.18033688011112042f

// ---------------- fp32 -> bf16 conversion (4 critical-path buffers) ----------
struct CvtArgs {
  const float* src[4];
  ushort* dst[4];
  int end[4];  // cumulative float4 counts
};

__global__ __launch_bounds__(256) void cvt_all_k(CvtArgs a, int total4) {
  for (int i = blockIdx.x * 256 + threadIdx.x; i < total4; i += gridDim.x * 256) {
    int seg = 0;
#pragma unroll
    for (int s = 0; s < 3; s++)
      if (i >= a.end[s]) seg = s + 1;
    int base = seg ? a.end[seg - 1] : 0;
    int j = i - base;
    float4 v = ((const float4*)a.src[seg])[j];
    ushort4 u;
    u.x = f2bf(v.x); u.y = f2bf(v.y); u.z = f2bf(v.z); u.w = f2bf(v.w);
    ((ushort4*)a.dst[seg])[j] = u;
  }
}

// ---- fat dispatch #1: QKV(768 blocks) + rk(512) + deferred cvt(512) --------
struct Cvt3 {
  const float* src[3];
  ushort* dst[3];
  int end[3];
};

__global__ __launch_bounds__(256) void fat_qkv_rk_cvt(
    const ushort* __restrict__ xb, const ushort* __restrict__ qkvw,
    const ushort* __restrict__ rb, const ushort* __restrict__ rnetw,
    ushort* __restrict__ qw, ushort* __restrict__ qr, ushort* __restrict__ kbuf,
    ushort* __restrict__ vt, ushort* __restrict__ rkout,
    const float* __restrict__ rwb, const float* __restrict__ rrb,
    Cvt3 cv, int cvt_total4) {
  __shared__ char smem[32768];
  const int bid = blockIdx.x;
  const int t = threadIdx.x;
  const int lane = t & 63, wv = t >> 6;
  const int wr = wv >> 1, wc = wv & 1;
  const int rif = lane & 15;
  const int kb = (lane >> 4) * 16;
  const int arow = t >> 2;
  const int acol = (t & 3) * 16;
  const int rbase = (lane >> 4) * 4;

  if (bid < 768) {
    // ---------- QKV: C[4096,3072] = xb × qkvw^T, 128² tile, 2-phase ----------
    const int bx = bid % 24, by = bid / 24;
    const int m0 = by * 128, n0 = bx * 128;
    const int K = 1024;
    const char* Ab = (const char*)xb;
    const char* Bb = (const char*)qkvw;

    f32x4 acc[4][4] = {};
    auto stage = [&](int b, int k0) {
      char* As = smem + b * 8192;
      char* Bs = smem + 16384 + b * 8192;
      size_t abase = ((size_t)(m0 + arow) * K + k0) * 2 + acol;
      gload_lds16(Ab + abase, As + t * 16);
      gload_lds16(Ab + abase + (size_t)64 * K * 2, As + t * 16 + 4096);
      size_t bbase = ((size_t)(n0 + arow) * K + k0) * 2 + acol;
      gload_lds16(Bb + bbase, Bs + t * 16);
      gload_lds16(Bb + bbase + (size_t)64 * K * 2, Bs + t * 16 + 4096);
    };

    stage(0, 0);
    asm volatile("s_waitcnt vmcnt(0)" ::: "memory");
    __builtin_amdgcn_s_barrier();
    __builtin_amdgcn_sched_barrier(0);

    int cur = 0;
#pragma unroll 1
    for (int k0 = 0; k0 < K; k0 += 32) {
      if (k0 + 32 < K) stage(cur ^ 1, k0 + 32);
      const char* As = smem + cur * 8192;
      const char* Bs = smem + 16384 + cur * 8192;
      bf16x8 af[4], bfr[4];
#pragma unroll
      for (int m = 0; m < 4; m++)
        af[m] = *(const bf16x8*)(As + (wr * 64 + m * 16 + rif) * 64 + kb);
#pragma unroll
      for (int n = 0; n < 4; n++)
        bfr[n] = *(const bf16x8*)(Bs + (wc * 64 + n * 16 + rif) * 64 + kb);
      __builtin_amdgcn_s_setprio(1);
#pragma unroll
      for (int m = 0; m < 4; m++)
#pragma unroll
        for (int n = 0; n < 4; n++)
          acc[m][n] = __builtin_amdgcn_mfma_f32_16x16x32_bf16(af[m], bfr[n], acc[m][n], 0, 0, 0);
      __builtin_amdgcn_s_setprio(0);
      asm volatile("s_waitcnt vmcnt(0)" ::: "memory");
      __builtin_amdgcn_s_barrier();
      __builtin_amdgcn_sched_barrier(0);
      cur ^= 1;
    }

#pragma unroll
    for (int m = 0; m < 4; m++) {
#pragma unroll
      for (int n = 0; n < 4; n++) {
#pragma unroll
        for (int reg = 0; reg < 4; reg++) {
          int gr = m0 + wr * 64 + m * 16 + rbase + reg;
          int gc = n0 + wc * 64 + n * 16 + (lane & 15);
          float v = acc[m][n][reg];
          int which = gc >> 10, hh = gc & 1023;
          int hn = hh >> 6, hd = hh & 63;
          int qi = gr >> 1, qb = gr & 1;
          size_t off = ((size_t)(qb * NHEAD + hn) * QL + qi) * 64 + hd;
          if (which == 0) {
            qw[off] = f2bf((v + rwb[hh]) * QSCALE);
            qr[off] = f2bf((v + rrb[hh]) * QSCALE);
          } else if (which == 1) {
            kbuf[off] = f2bf(v);
          } else {
            vt[((size_t)(qb * NHEAD + hn) * 64 + hd) * QL + qi] = f2bf(v);
          }
        }
      }
    }
  } else if (bid < 1280) {
    // ---------- rk: rkout = rb[2048,1024] × rnetw^T, 64² tile, 2-phase -------
    const int b = bid - 768;
    const int bx = b % 16, by = b / 16;
    const int m0 = by * 64, n0 = bx * 64;
    const int K = 1024;
    const char* Ab = (const char*)rb;
    const char* Bb = (const char*)rnetw;

    f32x4 acc[2][2] = {};
    auto stage = [&](int bb, int k0) {
      char* As = smem + bb * 4096;
      char* Bs = smem + 8192 + bb * 4096;
      size_t abase = ((size_t)(m0 + arow) * K + k0) * 2 + acol;
      gload_lds16(Ab + abase, As + t * 16);
      size_t bbase = ((size_t)(n0 + arow) * K + k0) * 2 + acol;
      gload_lds16(Bb + bbase, Bs + t * 16);
    };

    stage(0, 0);
    asm volatile("s_waitcnt vmcnt(0)" ::: "memory");
    __builtin_amdgcn_s_barrier();
    __builtin_amdgcn_sched_barrier(0);

    int cur = 0;
#pragma unroll 1
    for (int k0 = 0; k0 < K; k0 += 32) {
      if (k0 + 32 < K) stage(cur ^ 1, k0 + 32);
      const char* As = smem + cur * 4096;
      const char* Bs = smem + 8192 + cur * 4096;
      bf16x8 af[2], bfr[2];
#pragma unroll
      for (int m = 0; m < 2; m++)
        af[m] = *(const bf16x8*)(As + (wr * 32 + m * 16 + rif) * 64 + kb);
#pragma unroll
      for (int n = 0; n < 2; n++)
        bfr[n] = *(const bf16x8*)(Bs + (wc * 32 + n * 16 + rif) * 64 + kb);
      __builtin_amdgcn_s_setprio(1);
#pragma unroll
      for (int m = 0; m < 2; m++)
#pragma unroll
        for (int n = 0; n < 2; n++)
          acc[m][n] = __builtin_amdgcn_mfma_f32_16x16x32_bf16(af[m], bfr[n], acc[m][n], 0, 0, 0);
      __builtin_amdgcn_s_setprio(0);
      asm volatile("s_waitcnt vmcnt(0)" ::: "memory");
      __builtin_amdgcn_s_barrier();
      __builtin_amdgcn_sched_barrier(0);
      cur ^= 1;
    }

#pragma unroll
    for (int m = 0; m < 2; m++) {
#pragma unroll
      for (int n = 0; n < 2; n++) {
#pragma unroll
        for (int reg = 0; reg < 4; reg++) {
          int gr = m0 + wr * 32 + m * 16 + rbase + reg;
          int gc = n0 + wc * 32 + n * 16 + (lane & 15);
          int hn = gc >> 6, hd = gc & 63;
          rkout[((size_t)hn * QL + gr) * 64 + hd] = f2bf(acc[m][n][reg]);
        }
      }
    }
  } else {
    // ---------- deferred cvt of o_w, w1, w2 (not needed until after flash) ---
    for (int i = (bid - 1280) * 256 + t; i < cvt_total4; i += 512 * 256) {
      int seg = 0;
#pragma unroll
      for (int s = 0; s < 2; s++)
        if (i >= cv.end[s]) seg = s + 1;
      int base = seg ? cv.end[seg - 1] : 0;
      int j = i - base;
      float4 v = ((const float4*)cv.src[seg])[j];
      ushort4 u;
      u.x = f2bf(v.x); u.y = f2bf(v.y); u.z = f2bf(v.z); u.w = f2bf(v.w);
      ((ushort4*)cv.dst[seg])[j] = u;
    }
  }
}

// ---------------- FFN1 GEMM (R8-proven 2-phase, bias+relu+bf16) -------------
__global__ __launch_bounds__(256) void gemm_ffn1(
    const ushort* __restrict__ A, const ushort* __restrict__ B, int M, int N, int K,
    ushort* __restrict__ Cb, const float* __restrict__ bias) {
  __shared__ ushort As[2][128 * 32];
  __shared__ ushort Bs[2][128 * 32];
  const int t = threadIdx.x;
  const int lane = t & 63, wv = t >> 6;
  const int wr = wv >> 1, wc = wv & 1;
  const int m0 = blockIdx.y * 128, n0 = blockIdx.x * 128;
  const int rif = lane & 15;
  const int kb = (lane >> 4) * 16;

  f32x4 acc[4][4] = {};
  const char* Ab = (const char*)A;
  const char* Bb = (const char*)B;
  const int arow = t >> 2;
  const int acol = (t & 3) * 16;

  auto stage = [&](int b, int k0) {
    size_t abase = ((size_t)(m0 + arow) * K + k0) * 2 + acol;
    gload_lds16(Ab + abase, (char*)As[b] + t * 16);
    gload_lds16(Ab + abase + (size_t)64 * K * 2, (char*)As[b] + t * 16 + 4096);
    size_t bbase = ((size_t)(n0 + arow) * K + k0) * 2 + acol;
    gload_lds16(Bb + bbase, (char*)Bs[b] + t * 16);
    gload_lds16(Bb + bbase + (size_t)64 * K * 2, (char*)Bs[b] + t * 16 + 4096);
  };

  stage(0, 0);
  asm volatile("s_waitcnt vmcnt(0)" ::: "memory");
  __builtin_amdgcn_s_barrier();
  __builtin_amdgcn_sched_barrier(0);

  int cur = 0;
#pragma unroll 1
  for (int k0 = 0; k0 < K; k0 += 32) {
    if (k0 + 32 < K) stage(cur ^ 1, k0 + 32);
    bf16x8 af[4], bfr[4];
#pragma unroll
    for (int m = 0; m < 4; m++)
      af[m] = *(const bf16x8*)((const char*)As[cur] + (wr * 64 + m * 16 + rif) * 64 + kb);
#pragma unroll
    for (int n = 0; n < 4; n++)
      bfr[n] = *(const bf16x8*)((const char*)Bs[cur] + (wc * 64 + n * 16 + rif) * 64 + kb);
    __builtin_amdgcn_s_setprio(1);
#pragma unroll
    for (int m = 0; m < 4; m++)
#pragma unroll
      for (int n = 0; n < 4; n++)
        acc[m][n] = __builtin_amdgcn_mfma_f32_16x16x32_bf16(af[m], bfr[n], acc[m][n], 0, 0, 0);
    __builtin_amdgcn_s_setprio(0);
    asm volatile("s_waitcnt vmcnt(0)" ::: "memory");
    __builtin_amdgcn_s_barrier();
    __builtin_amdgcn_sched_barrier(0);
    cur ^= 1;
  }

  const int rbase = (lane >> 4) * 4;
#pragma unroll
  for (int m = 0; m < 4; m++) {
#pragma unroll
    for (int n = 0; n < 4; n++) {
#pragma unroll
      for (int reg = 0; reg < 4; reg++) {
        int gr = m0 + wr * 64 + m * 16 + rbase + reg;
        int gc = n0 + wc * 64 + n * 16 + (lane & 15);
        Cb[(size_t)gr * N + gc] = f2bf(fmaxf(acc[m][n][reg] + bias[gc], 0.f));
      }
    }
  }
}

// ---- split-K BN=64 GEMM for N=1024 (o-proj, FFN2), bf16 partials ----------
template <int WITH_BIAS>
__global__ __launch_bounds__(256) void gemm_nt64sk(
    const ushort* __restrict__ A, const ushort* __restrict__ B, int M, int N, int Kfull,
    int Klen, ushort* __restrict__ Cb0, ushort* __restrict__ Cb1,
    const float* __restrict__ bias) {
  __shared__ ushort As[2][128 * 32];
  __shared__ ushort Bs[2][64 * 32];
  const int t = threadIdx.x;
  const int lane = t & 63, wv = t >> 6;
  const int wr = wv >> 1, wc = wv & 1;
  const int m0 = blockIdx.y * 128, n0 = blockIdx.x * 64;
  const int z = blockIdx.z;
  const int koff = z * Klen;
  ushort* Cb = z ? Cb1 : Cb0;
  const int rif = lane & 15;
  const int kb = (lane >> 4) * 16;

  f32x4 acc[4][2] = {};
  const char* Ab = (const char*)A;
  const char* Bb = (const char*)B;
  const int arow = t >> 2;
  const int acol = (t & 3) * 16;

  auto stage = [&](int b, int k0) {
    size_t abase = ((size_t)(m0 + arow) * Kfull + koff + k0) * 2 + acol;
    gload_lds16(Ab + abase, (char*)As[b] + t * 16);
    gload_lds16(Ab + abase + (size_t)64 * Kfull * 2, (char*)As[b] + t * 16 + 4096);
    size_t bbase = ((size_t)(n0 + arow) * Kfull + koff + k0) * 2 + acol;
    gload_lds16(Bb + bbase, (char*)Bs[b] + t * 16);
  };

  stage(0, 0);
  asm volatile("s_waitcnt vmcnt(0)" ::: "memory");
  __builtin_amdgcn_s_barrier();
  __builtin_amdgcn_sched_barrier(0);

  int cur = 0;
#pragma unroll 1
  for (int k0 = 0; k0 < Klen; k0 += 32) {
    if (k0 + 32 < Klen) stage(cur ^ 1, k0 + 32);
    bf16x8 af[4], bfr[2];
#pragma unroll
    for (int m = 0; m < 4; m++)
      af[m] = *(const bf16x8*)((const char*)As[cur] + (wr * 64 + m * 16 + rif) * 64 + kb);
#pragma unroll
    for (int n = 0; n < 2; n++)
      bfr[n] = *(const bf16x8*)((const char*)Bs[cur] + (wc * 32 + n * 16 + rif) * 64 + kb);
    __builtin_amdgcn_s_setprio(1);
#pragma unroll
    for (int m = 0; m < 4; m++)
#pragma unroll
      for (int n = 0; n < 2; n++)
        acc[m][n] = __builtin_amdgcn_mfma_f32_16x16x32_bf16(af[m], bfr[n], acc[m][n], 0, 0, 0);
    __builtin_amdgcn_s_setprio(0);
    asm volatile("s_waitcnt vmcnt(0)" ::: "memory");
    __builtin_amdgcn_s_barrier();
    __builtin_amdgcn_sched_barrier(0);
    cur ^= 1;
  }

  const int rbase = (lane >> 4) * 4;
#pragma unroll
  for (int m = 0; m < 4; m++) {
#pragma unroll
    for (int n = 0; n < 2; n++) {
#pragma unroll
      for (int reg = 0; reg < 4; reg++) {
        int gr = m0 + wr * 64 + m * 16 + rbase + reg;
        int gc = n0 + wc * 32 + n * 16 + (lane & 15);
        float v = acc[m][n][reg];
        if (WITH_BIAS && z == 0) v += bias[gc];
        Cb[(size_t)gr * N + gc] = f2bf(v);
      }
    }
  }
}

// ---------------- fused causal attention (R10/R12-proven) -------------------
__global__ __launch_bounds__(256) void flash_attn(
    const ushort* __restrict__ Qw, const ushort* __restrict__ Qr,
    const ushort* __restrict__ Kb, const ushort* __restrict__ Vt,
    const ushort* __restrict__ Rk, ushort* __restrict__ out) {
  __shared__ ushort K_lds[2][64 * 64];
  __shared__ ushort V_lds[2][64 * 64];   // [d][j], swizzled
  __shared__ ushort R_lds[2][128 * 64];  // rows T0..T0+127, swizzled
  __shared__ ushort P_lds[4][16 * 64];   // per-wave P, swizzled rows

  const int t = threadIdx.x;
  const int lane = t & 63, wv = t >> 6;
  const int bn = blockIdx.y;
  const int qb = bn >> 4, hn = bn & 15;
  const int c4 = lane & 15, g4 = lane >> 4;

  const char* Qwb = (const char*)(Qw + (size_t)bn * QL * 64);
  const char* Qrb = (const char*)(Qr + (size_t)bn * QL * 64);
  const char* Kbb = (const char*)(Kb + (size_t)bn * QL * 64);
  const char* Vtb = (const char*)(Vt + (size_t)bn * 64 * QL);
  const char* Rkb = (const char*)(Rk + (size_t)hn * QL * 64);

  int addrs[4];
#pragma unroll
  for (int reg = 0; reg < 4; reg++) {
    int rr = g4 * 4 + reg;
    addrs[reg] = ((lane & 48) | ((c4 + 15 - rr) & 15)) << 2;
  }

#pragma unroll 1
  for (int ph = 0; ph < 2; ph++) {
    const int itile = (ph == 0) ? (31 - (int)blockIdx.x) : (int)blockIdx.x;
    const int i0 = itile * 64;
    const int iw = i0 + wv * 16;
    const int niter = itile + 1;

    bf16x8 qwf[2], qrf[2];
#pragma unroll
    for (int kk = 0; kk < 2; kk++) {
      qwf[kk] = *(const bf16x8*)(Qwb + (size_t)(iw + c4) * 128 + kk * 64 + g4 * 16);
      qrf[kk] = *(const bf16x8*)(Qrb + (size_t)(iw + c4) * 128 + kk * 64 + g4 * 16);
    }

    f32x4 o_acc[4] = {};
    float m_run[4], l_run[4];
#pragma unroll
    for (int r = 0; r < 4; r++) { m_run[r] = -3.0e38f; l_run[r] = 0.f; }

    auto stage = [&](int b, int j0) {
      const int T0 = j0 - i0 + (QL - 64);
#pragma unroll
      for (int p = 0; p < 2; p++) {
        int o = t * 16 + p * 4096;
        int row = o >> 7, ch16 = ((((o & 127) >> 4) ^ (row & 7)) << 4);
        gload_lds16(Kbb + (size_t)(j0 + row) * 128 + ch16, (char*)K_lds[b] + o);
        gload_lds16(Vtb + (size_t)row * (QL * 2) + (size_t)j0 * 2 + ch16, (char*)V_lds[b] + o);
      }
#pragma unroll
      for (int p = 0; p < 4; p++) {
        int o = t * 16 + p * 4096;
        int r = o >> 7;
        int srow = T0 + r; srow = srow > QL - 1 ? QL - 1 : srow;  // masked cells only
        int ch16 = ((((o & 127) >> 4) ^ (r & 7)) << 4);
        gload_lds16(Rkb + (size_t)srow * 128 + ch16, (char*)R_lds[b] + o);
      }
    };

    auto tile_body = [&](int j0, int cur, auto mc) {
      constexpr bool MASKED = decltype(mc)::value;
      f32x4 acc_s[4] = {};
      f32x4 acc_bd[5] = {};
      const int baseloc = 48 - wv * 16;
      __builtin_amdgcn_s_setprio(1);
#pragma unroll
      for (int kk = 0; kk < 2; kk++) {
        const int sw = (((kk * 4 + g4) ^ (c4 & 7)) << 4);
#pragma unroll
        for (int nf = 0; nf < 4; nf++) {
          bf16x8 bk = *(const bf16x8*)((const char*)K_lds[cur] + (nf * 16 + c4) * 128 + sw);
          acc_s[nf] = __builtin_amdgcn_mfma_f32_16x16x32_bf16(qwf[kk], bk, acc_s[nf], 0, 0, 0);
        }
#pragma unroll
        for (int tf = 0; tf < 5; tf++) {
          int oo = baseloc + tf * 16 + c4;  // oo&7 == c4&7
          bf16x8 br = *(const bf16x8*)((const char*)R_lds[cur] + oo * 128 + sw);
          acc_bd[tf] = __builtin_amdgcn_mfma_f32_16x16x32_bf16(qrf[kk], br, acc_bd[tf], 0, 0, 0);
        }
      }
      __builtin_amdgcn_s_setprio(0);

      uint32_t pk[4][4];
#pragma unroll
      for (int nf = 0; nf < 4; nf++)
#pragma unroll
        for (int reg = 0; reg < 4; reg++)
          asm("v_cvt_pk_bf16_f32 %0, %1, %2"
              : "=v"(pk[nf][reg])
              : "v"(acc_bd[nf][reg]), "v"(acc_bd[nf + 1][reg]));

      float sv[4][4];
      float rowmax[4] = {-3.0e38f, -3.0e38f, -3.0e38f, -3.0e38f};
#pragma unroll
      for (int nf = 0; nf < 4; nf++) {
#pragma unroll
        for (int reg = 0; reg < 4; reg++) {
          int rr = g4 * 4 + reg;
          uint32_t pulled = (uint32_t)__builtin_amdgcn_ds_bpermute(addrs[reg], (int)pk[nf][reg]);
          uint32_t bits = (c4 > rr) ? (pulled & 0xffff0000u) : (pulled << 16);
          float v = acc_s[nf][reg] + __uint_as_float(bits);
          if (MASKED) {
            int jg = j0 + nf * 16 + c4;
            int ig = iw + rr;
            v = (jg <= ig) ? v : -3.0e38f;
          }
          sv[nf][reg] = v;
          rowmax[reg] = fmaxf(rowmax[reg], v);
        }
      }
#pragma unroll
      for (int reg = 0; reg < 4; reg++) {
        float rm = rowmax[reg];
        rm = fmaxf(rm, __shfl_xor(rm, 1));
        rm = fmaxf(rm, __shfl_xor(rm, 2));
        rm = fmaxf(rm, __shfl_xor(rm, 4));
        rm = fmaxf(rm, __shfl_xor(rm, 8));
        float mnew = fmaxf(m_run[reg], rm);
        float alpha = __builtin_amdgcn_exp2f(m_run[reg] - mnew);
        float rsum = 0.f;
#pragma unroll
        for (int nf = 0; nf < 4; nf++) {
          float p = __builtin_amdgcn_exp2f(sv[nf][reg] - mnew);
          sv[nf][reg] = p;
          rsum += p;
        }
        rsum += __shfl_xor(rsum, 1);
        rsum += __shfl_xor(rsum, 2);
        rsum += __shfl_xor(rsum, 4);
        rsum += __shfl_xor(rsum, 8);
        l_run[reg] = l_run[reg] * alpha + rsum;
        m_run[reg] = mnew;
#pragma unroll
        for (int df = 0; df < 4; df++) o_acc[df][reg] *= alpha;
      }

      {
        char* pb = (char*)P_lds[wv];
#pragma unroll
        for (int nf = 0; nf < 4; nf++)
#pragma unroll
          for (int reg = 0; reg < 4; reg++) {
            int row = g4 * 4 + reg, col = nf * 16 + c4;
            int byt = row * 128 + ((((col >> 3) ^ (row & 7))) << 4) + (col & 7) * 2;
            *(ushort*)(pb + byt) = f2bf(sv[nf][reg]);
          }
      }
      __builtin_amdgcn_s_setprio(1);
#pragma unroll
      for (int kk = 0; kk < 2; kk++) {
        const char* pb = (const char*)P_lds[wv];
        bf16x8 pa = *(const bf16x8*)(pb + c4 * 128 + (((kk * 4 + g4) ^ (c4 & 7)) << 4));
        const int sw = (((kk * 4 + g4) ^ (c4 & 7)) << 4);
#pragma unroll
        for (int df = 0; df < 4; df++) {
          bf16x8 bv = *(const bf16x8*)((const char*)V_lds[cur] + (df * 16 + c4) * 128 + sw);
          o_acc[df] = __builtin_amdgcn_mfma_f32_16x16x32_bf16(pa, bv, o_acc[df], 0, 0, 0);
        }
      }
      __builtin_amdgcn_s_setprio(0);
    };

    stage(0, 0);
    asm volatile("s_waitcnt vmcnt(0)" ::: "memory");
    __builtin_amdgcn_s_barrier();
    __builtin_amdgcn_sched_barrier(0);

    int cur = 0;
#pragma unroll 1
    for (int it = 0; it < niter - 1; ++it) {
      stage(cur ^ 1, (it + 1) * 64);
      tile_body(it * 64, cur, BoolC<false>{});
      asm volatile("s_waitcnt vmcnt(0)" ::: "memory");
      __builtin_amdgcn_s_barrier();
      __builtin_amdgcn_sched_barrier(0);
      cur ^= 1;
    }
    tile_body(i0, cur, BoolC<true>{});
    __syncthreads();

#pragma unroll
    for (int reg = 0; reg < 4; reg++) {
      float inv = 1.0f / l_run[reg];
      int ig = iw + g4 * 4 + reg;
      size_t grow = (size_t)(ig * 2 + qb) * 1024 + hn * 64;
#pragma unroll
      for (int df = 0; df < 4; df++)
        out[grow + df * 16 + c4] = f2bf(o_acc[df][reg] * inv);
    }
  }
}

// ---------------- residual + 2 bf16 partials + LayerNorm --------------------
template <bool WB>
__global__ __launch_bounds__(256) void ln_res3(
    const float* __restrict__ xa, const ushort* __restrict__ xb0,
    const ushort* __restrict__ xb1, const float* __restrict__ g,
    const float* __restrict__ bt, float* __restrict__ of, ushort* __restrict__ ob) {
  __shared__ float red[8];
  const int row = blockIdx.x;
  const int t = threadIdx.x;
  const int lane = t & 63, wv = t >> 6;
  const float4 a = *(const float4*)(xa + (size_t)row * 1024 + t * 4);
  const ushort4 c0 = *(const ushort4*)(xb0 + (size_t)row * 1024 + t * 4);
  const ushort4 c1 = *(const ushort4*)(xb1 + (size_t)row * 1024 + t * 4);
  float x[4] = {a.x + bf2f(c0.x) + bf2f(c1.x), a.y + bf2f(c0.y) + bf2f(c1.y),
                a.z + bf2f(c0.z) + bf2f(c1.z), a.w + bf2f(c0.w) + bf2f(c1.w)};
  float s = x[0] + x[1] + x[2] + x[3];
  for (int m = 1; m < 64; m <<= 1) s += __shfl_xor(s, m);
  if (lane == 0) red[wv] = s;
  __syncthreads();
  float mu = (red[0] + red[1] + red[2] + red[3]) * (1.f / 1024.f);
  float d[4];
  float ss = 0.f;
#pragma unroll
  for (int i = 0; i < 4; i++) { d[i] = x[i] - mu; ss += d[i] * d[i]; }
  for (int m = 1; m < 64; m <<= 1) ss += __shfl_xor(ss, m);
  if (lane == 0) red[4 + wv] = ss;
  __syncthreads();
  float var = (red[4] + red[5] + red[6] + red[7]) * (1.f / 1024.f);
  float rs = rsqrtf(var + 1e-5f);
  float4 gv = *(const float4*)(g + t * 4);
  float4 bv = *(const float4*)(bt + t * 4);
  float y[4] = {d[0] * rs * gv.x + bv.x, d[1] * rs * gv.y + bv.y,
                d[2] * rs * gv.z + bv.z, d[3] * rs * gv.w + bv.w};
  float4 yo = make_float4(y[0], y[1], y[2], y[3]);
  *(float4*)(of + (size_t)row * 1024 + t * 4) = yo;
  if (WB) {
    ushort4 u;
    u.x = f2bf(y[0]); u.y = f2bf(y[1]); u.z = f2bf(y[2]); u.w = f2bf(y[3]);
    *(ushort4*)(ob + (size_t)row * 1024 + t * 4) = u;
  }
}

// ---------------- host orchestration ----------------
extern "C" void kernel_launch(void* const* d_in, const int* in_sizes, int n_in,
                              void* d_out, int out_size, void* d_ws, size_t ws_size,
                              hipStream_t stream) {
  const float* dec_inp = (const float*)d_in[0];
  const float* r_in = (const float*)d_in[1];
  const float* rwb = (const float*)d_in[2];
  const float* rrb = (const float*)d_in[3];
  const float* qkv_w = (const float*)d_in[4];
  const float* rnet_w = (const float*)d_in[5];
  const float* o_w = (const float*)d_in[6];
  const float* ln_attn_g = (const float*)d_in[7];
  const float* ln_attn_b = (const float*)d_in[8];
  const float* w1 = (const float*)d_in[9];
  const float* b1 = (const float*)d_in[10];
  const float* w2 = (const float*)d_in[11];
  const float* b2 = (const float*)d_in[12];
  const float* ln_ff_g = (const float*)d_in[13];
  const float* ln_ff_b = (const float*)d_in[14];
  float* out = (float*)d_out;

  char* ws = (char*)d_ws;
  size_t off = 0;
  auto alloc = [&](size_t bytes) {
    char* p = ws + off;
    off += (bytes + 255) & ~(size_t)255;
    return p;
  };
  const int ROWS = QL * 2;
  ushort* qkvw_b = (ushort*)alloc((size_t)3072 * 1024 * 2);
  ushort* rnetw_b = (ushort*)alloc((size_t)1024 * 1024 * 2);
  ushort* ow_b = (ushort*)alloc((size_t)1024 * 1024 * 2);
  ushort* w1_b = (ushort*)alloc((size_t)4096 * 1024 * 2);
  ushort* w2_b = (ushort*)alloc((size_t)1024 * 4096 * 2);
  ushort* x_b = (ushort*)alloc((size_t)ROWS * 1024 * 2);
  ushort* r_b = (ushort*)alloc((size_t)QL * 1024 * 2);
  ushort* Qw = (ushort*)alloc((size_t)32 * QL * 64 * 2);
  ushort* Qr = (ushort*)alloc((size_t)32 * QL * 64 * 2);
  ushort* Kb = (ushort*)alloc((size_t)32 * QL * 64 * 2);
  ushort* Vt = (ushort*)alloc((size_t)32 * 64 * QL * 2);
  ushort* rk = (ushort*)alloc((size_t)16 * QL * 64 * 2);
  ushort* avec = (ushort*)alloc((size_t)ROWS * 1024 * 2);
  ushort* p0 = (ushort*)alloc((size_t)ROWS * 1024 * 2);
  ushort* p1 = (ushort*)alloc((size_t)ROWS * 1024 * 2);
  float* x1f = (float*)alloc((size_t)ROWS * 1024 * 4);
  ushort* x1b = (ushort*)alloc((size_t)ROWS * 1024 * 2);
  ushort* hidden = (ushort*)alloc((size_t)ROWS * 4096 * 2);
  ushort* q0 = (ushort*)alloc((size_t)ROWS * 1024 * 2);
  ushort* q1 = (ushort*)alloc((size_t)ROWS * 1024 * 2);

  // critical-path conversions: qkv_w, rnet_w, dec_inp, r
  CvtArgs ca;
  {
    int n4[4] = {3072 * 1024 / 4, 1024 * 1024 / 4, ROWS * 1024 / 4, QL * 1024 / 4};
    const float* srcs[4] = {qkv_w, rnet_w, dec_inp, r_in};
    ushort* dsts[4] = {qkvw_b, rnetw_b, x_b, r_b};
    int cum = 0;
    for (int i = 0; i < 4; i++) {
      ca.src[i] = srcs[i];
      ca.dst[i] = dsts[i];
      cum += n4[i];
      ca.end[i] = cum;
    }
    cvt_all_k<<<2048, 256, 0, stream>>>(ca, cum);
  }

  // fat dispatch: QKV proj + rk proj + deferred cvt of o_w/w1/w2
  Cvt3 cv;
  int cvt_total4;
  {
    int n4[3] = {1024 * 1024 / 4, 4096 * 1024 / 4, 1024 * 4096 / 4};
    const float* srcs[3] = {o_w, w1, w2};
    ushort* dsts[3] = {ow_b, w1_b, w2_b};
    int cum = 0;
    for (int i = 0; i < 3; i++) {
      cv.src[i] = srcs[i];
      cv.dst[i] = dsts[i];
      cum += n4[i];
      cv.end[i] = cum;
    }
    cvt_total4 = cum;
  }
  fat_qkv_rk_cvt<<<1792, 256, 0, stream>>>(x_b, qkvw_b, r_b, rnetw_b, Qw, Qr, Kb, Vt, rk,
                                           rwb, rrb, cv, cvt_total4);

  flash_attn<<<dim3(16, 32), 256, 0, stream>>>(Qw, Qr, Kb, Vt, rk, avec);
  // o-proj split-K=2 (K=512 each), bf16 partials p0/p1
  gemm_nt64sk<0><<<dim3(1024 / 64, ROWS / 128, 2), 256, 0, stream>>>(
      avec, ow_b, ROWS, 1024, 1024, 512, p0, p1, nullptr);
  ln_res3<true><<<ROWS, 256, 0, stream>>>(dec_inp, p0, p1, ln_attn_g, ln_attn_b, x1f, x1b);
  gemm_ffn1<<<dim3(4096 / 128, ROWS / 128), 256, 0, stream>>>(
      x1b, w1_b, ROWS, 4096, 1024, hidden, b1);
  // FFN2 split-K=2 (K=2048 each), bias folded into z==0 partial
  gemm_nt64sk<1><<<dim3(1024 / 64, ROWS / 128, 2), 256, 0, stream>>>(
      hidden, w2_b, ROWS, 1024, 4096, 2048, q0, q1, b2);
  ln_res3<false><<<ROWS, 256, 0, stream>>>(x1f, q0, q1, ln_ff_g, ln_ff_b, out, nullptr);
}

// Round 15
// 325.051 us; speedup vs baseline: 1.3464x; 1.0383x over previous
//
#include <hip/hip_runtime.h>
#include <stdint.h>

#define QL 2048
#define NHEAD 16
#define DHEAD 64
#define DMODEL 1024
#define DINNER 4096

typedef __attribute__((ext_vector_type(8))) short bf16x8;
typedef __attribute__((ext_vector_type(4))) float f32x4;

template <bool V>
struct BoolC { static constexpr bool value = V; };

__device__ __forceinline__ ushort f2bf(float f) {
  uint32_t u = __float_as_uint(f);
  u = (u + 0x7fffu + ((u >> 16) & 1u)) >> 16;
  return (ushort)u;
}
__device__ __forceinline__ float bf2f(ushort u) {
  return __uint_as_float(((uint32_t)u) << 16);
}

__device__ __forceinline__ void gload_lds16(const void* g, void* l) {
  auto gp = reinterpret_cast<const uint32_t __attribute__((address_space(1)))*>(
      reinterpret_cast<uintptr_t>(g));
  auto lp = reinterpret_cast<uint32_t __attribute__((address_space(3)))*>(
      (uint32_t)reinterpret_cast<uintptr_t>(l));
  __builtin_amdgcn_global_load_lds(gp, lp, 16, 0, 0);
}

// softmax scale folded into Q at projection: 0.125 * log2(e)
#define QSCALE 0.18033688011112042f

// ---------------- fp32 -> bf16 conversion (4 critical-path buffers) ----------
struct CvtArgs {
  const float* src[4];
  ushort* dst[4];
  int end[4];  // cumulative float4 counts
};

__global__ __launch_bounds__(256) void cvt_all_k(CvtArgs a, int total4) {
  for (int i = blockIdx.x * 256 + threadIdx.x; i < total4; i += gridDim.x * 256) {
    int seg = 0;
#pragma unroll
    for (int s = 0; s < 3; s++)
      if (i >= a.end[s]) seg = s + 1;
    int base = seg ? a.end[seg - 1] : 0;
    int j = i - base;
    float4 v = ((const float4*)a.src[seg])[j];
    ushort4 u;
    u.x = f2bf(v.x); u.y = f2bf(v.y); u.z = f2bf(v.z); u.w = f2bf(v.w);
    ((ushort4*)a.dst[seg])[j] = u;
  }
}

// ---- fat dispatch #1: QKV(768 blocks) + rk(512) + deferred cvt(512) --------
struct Cvt3 {
  const float* src[3];
  ushort* dst[3];
  int end[3];
};

__global__ __launch_bounds__(256) void fat_qkv_rk_cvt(
    const ushort* __restrict__ xb, const ushort* __restrict__ qkvw,
    const ushort* __restrict__ rb, const ushort* __restrict__ rnetw,
    ushort* __restrict__ qw, ushort* __restrict__ qr, ushort* __restrict__ kbuf,
    ushort* __restrict__ vt, ushort* __restrict__ rkout,
    const float* __restrict__ rwb, const float* __restrict__ rrb,
    Cvt3 cv, int cvt_total4) {
  __shared__ char smem[32768];
  const int bid = blockIdx.x;
  const int t = threadIdx.x;
  const int lane = t & 63, wv = t >> 6;
  const int wr = wv >> 1, wc = wv & 1;
  const int rif = lane & 15;
  const int kb = (lane >> 4) * 16;
  const int arow = t >> 2;
  const int acol = (t & 3) * 16;
  const int rbase = (lane >> 4) * 4;

  if (bid < 768) {
    // ---------- QKV: C[4096,3072] = xb × qkvw^T, 128² tile, 2-phase ----------
    const int bx = bid % 24, by = bid / 24;
    const int m0 = by * 128, n0 = bx * 128;
    const int K = 1024;
    const char* Ab = (const char*)xb;
    const char* Bb = (const char*)qkvw;

    f32x4 acc[4][4] = {};
    auto stage = [&](int b, int k0) {
      char* As = smem + b * 8192;
      char* Bs = smem + 16384 + b * 8192;
      size_t abase = ((size_t)(m0 + arow) * K + k0) * 2 + acol;
      gload_lds16(Ab + abase, As + t * 16);
      gload_lds16(Ab + abase + (size_t)64 * K * 2, As + t * 16 + 4096);
      size_t bbase = ((size_t)(n0 + arow) * K + k0) * 2 + acol;
      gload_lds16(Bb + bbase, Bs + t * 16);
      gload_lds16(Bb + bbase + (size_t)64 * K * 2, Bs + t * 16 + 4096);
    };

    stage(0, 0);
    asm volatile("s_waitcnt vmcnt(0)" ::: "memory");
    __builtin_amdgcn_s_barrier();
    __builtin_amdgcn_sched_barrier(0);

    int cur = 0;
#pragma unroll 1
    for (int k0 = 0; k0 < K; k0 += 32) {
      if (k0 + 32 < K) stage(cur ^ 1, k0 + 32);
      const char* As = smem + cur * 8192;
      const char* Bs = smem + 16384 + cur * 8192;
      bf16x8 af[4], bfr[4];
#pragma unroll
      for (int m = 0; m < 4; m++)
        af[m] = *(const bf16x8*)(As + (wr * 64 + m * 16 + rif) * 64 + kb);
#pragma unroll
      for (int n = 0; n < 4; n++)
        bfr[n] = *(const bf16x8*)(Bs + (wc * 64 + n * 16 + rif) * 64 + kb);
      __builtin_amdgcn_s_setprio(1);
#pragma unroll
      for (int m = 0; m < 4; m++)
#pragma unroll
        for (int n = 0; n < 4; n++)
          acc[m][n] = __builtin_amdgcn_mfma_f32_16x16x32_bf16(af[m], bfr[n], acc[m][n], 0, 0, 0);
      __builtin_amdgcn_s_setprio(0);
      asm volatile("s_waitcnt vmcnt(0)" ::: "memory");
      __builtin_amdgcn_s_barrier();
      __builtin_amdgcn_sched_barrier(0);
      cur ^= 1;
    }

#pragma unroll
    for (int m = 0; m < 4; m++) {
#pragma unroll
      for (int n = 0; n < 4; n++) {
#pragma unroll
        for (int reg = 0; reg < 4; reg++) {
          int gr = m0 + wr * 64 + m * 16 + rbase + reg;
          int gc = n0 + wc * 64 + n * 16 + (lane & 15);
          float v = acc[m][n][reg];
          int which = gc >> 10, hh = gc & 1023;
          int hn = hh >> 6, hd = hh & 63;
          int qi = gr >> 1, qb = gr & 1;
          size_t off = ((size_t)(qb * NHEAD + hn) * QL + qi) * 64 + hd;
          if (which == 0) {
            qw[off] = f2bf((v + rwb[hh]) * QSCALE);
            qr[off] = f2bf((v + rrb[hh]) * QSCALE);
          } else if (which == 1) {
            kbuf[off] = f2bf(v);
          } else {
            vt[((size_t)(qb * NHEAD + hn) * 64 + hd) * QL + qi] = f2bf(v);
          }
        }
      }
    }
  } else if (bid < 1280) {
    // ---------- rk: rkout = rb[2048,1024] × rnetw^T, 64² tile, 2-phase -------
    const int b = bid - 768;
    const int bx = b % 16, by = b / 16;
    const int m0 = by * 64, n0 = bx * 64;
    const int K = 1024;
    const char* Ab = (const char*)rb;
    const char* Bb = (const char*)rnetw;

    f32x4 acc[2][2] = {};
    auto stage = [&](int bb, int k0) {
      char* As = smem + bb * 4096;
      char* Bs = smem + 8192 + bb * 4096;
      size_t abase = ((size_t)(m0 + arow) * K + k0) * 2 + acol;
      gload_lds16(Ab + abase, As + t * 16);
      size_t bbase = ((size_t)(n0 + arow) * K + k0) * 2 + acol;
      gload_lds16(Bb + bbase, Bs + t * 16);
    };

    stage(0, 0);
    asm volatile("s_waitcnt vmcnt(0)" ::: "memory");
    __builtin_amdgcn_s_barrier();
    __builtin_amdgcn_sched_barrier(0);

    int cur = 0;
#pragma unroll 1
    for (int k0 = 0; k0 < K; k0 += 32) {
      if (k0 + 32 < K) stage(cur ^ 1, k0 + 32);
      const char* As = smem + cur * 4096;
      const char* Bs = smem + 8192 + cur * 4096;
      bf16x8 af[2], bfr[2];
#pragma unroll
      for (int m = 0; m < 2; m++)
        af[m] = *(const bf16x8*)(As + (wr * 32 + m * 16 + rif) * 64 + kb);
#pragma unroll
      for (int n = 0; n < 2; n++)
        bfr[n] = *(const bf16x8*)(Bs + (wc * 32 + n * 16 + rif) * 64 + kb);
      __builtin_amdgcn_s_setprio(1);
#pragma unroll
      for (int m = 0; m < 2; m++)
#pragma unroll
        for (int n = 0; n < 2; n++)
          acc[m][n] = __builtin_amdgcn_mfma_f32_16x16x32_bf16(af[m], bfr[n], acc[m][n], 0, 0, 0);
      __builtin_amdgcn_s_setprio(0);
      asm volatile("s_waitcnt vmcnt(0)" ::: "memory");
      __builtin_amdgcn_s_barrier();
      __builtin_amdgcn_sched_barrier(0);
      cur ^= 1;
    }

#pragma unroll
    for (int m = 0; m < 2; m++) {
#pragma unroll
      for (int n = 0; n < 2; n++) {
#pragma unroll
        for (int reg = 0; reg < 4; reg++) {
          int gr = m0 + wr * 32 + m * 16 + rbase + reg;
          int gc = n0 + wc * 32 + n * 16 + (lane & 15);
          int hn = gc >> 6, hd = gc & 63;
          rkout[((size_t)hn * QL + gr) * 64 + hd] = f2bf(acc[m][n][reg]);
        }
      }
    }
  } else {
    // ---------- deferred cvt of o_w, w1, w2 (not needed until after flash) ---
    for (int i = (bid - 1280) * 256 + t; i < cvt_total4; i += 512 * 256) {
      int seg = 0;
#pragma unroll
      for (int s = 0; s < 2; s++)
        if (i >= cv.end[s]) seg = s + 1;
      int base = seg ? cv.end[seg - 1] : 0;
      int j = i - base;
      float4 v = ((const float4*)cv.src[seg])[j];
      ushort4 u;
      u.x = f2bf(v.x); u.y = f2bf(v.y); u.z = f2bf(v.z); u.w = f2bf(v.w);
      ((ushort4*)cv.dst[seg])[j] = u;
    }
  }
}

// ---------------- FFN1 GEMM (R8-proven 2-phase, bias+relu+bf16) -------------
__global__ __launch_bounds__(256) void gemm_ffn1(
    const ushort* __restrict__ A, const ushort* __restrict__ B, int M, int N, int K,
    ushort* __restrict__ Cb, const float* __restrict__ bias) {
  __shared__ ushort As[2][128 * 32];
  __shared__ ushort Bs[2][128 * 32];
  const int t = threadIdx.x;
  const int lane = t & 63, wv = t >> 6;
  const int wr = wv >> 1, wc = wv & 1;
  const int m0 = blockIdx.y * 128, n0 = blockIdx.x * 128;
  const int rif = lane & 15;
  const int kb = (lane >> 4) * 16;

  f32x4 acc[4][4] = {};
  const char* Ab = (const char*)A;
  const char* Bb = (const char*)B;
  const int arow = t >> 2;
  const int acol = (t & 3) * 16;

  auto stage = [&](int b, int k0) {
    size_t abase = ((size_t)(m0 + arow) * K + k0) * 2 + acol;
    gload_lds16(Ab + abase, (char*)As[b] + t * 16);
    gload_lds16(Ab + abase + (size_t)64 * K * 2, (char*)As[b] + t * 16 + 4096);
    size_t bbase = ((size_t)(n0 + arow) * K + k0) * 2 + acol;
    gload_lds16(Bb + bbase, (char*)Bs[b] + t * 16);
    gload_lds16(Bb + bbase + (size_t)64 * K * 2, (char*)Bs[b] + t * 16 + 4096);
  };

  stage(0, 0);
  asm volatile("s_waitcnt vmcnt(0)" ::: "memory");
  __builtin_amdgcn_s_barrier();
  __builtin_amdgcn_sched_barrier(0);

  int cur = 0;
#pragma unroll 1
  for (int k0 = 0; k0 < K; k0 += 32) {
    if (k0 + 32 < K) stage(cur ^ 1, k0 + 32);
    bf16x8 af[4], bfr[4];
#pragma unroll
    for (int m = 0; m < 4; m++)
      af[m] = *(const bf16x8*)((const char*)As[cur] + (wr * 64 + m * 16 + rif) * 64 + kb);
#pragma unroll
    for (int n = 0; n < 4; n++)
      bfr[n] = *(const bf16x8*)((const char*)Bs[cur] + (wc * 64 + n * 16 + rif) * 64 + kb);
    __builtin_amdgcn_s_setprio(1);
#pragma unroll
    for (int m = 0; m < 4; m++)
#pragma unroll
      for (int n = 0; n < 4; n++)
        acc[m][n] = __builtin_amdgcn_mfma_f32_16x16x32_bf16(af[m], bfr[n], acc[m][n], 0, 0, 0);
    __builtin_amdgcn_s_setprio(0);
    asm volatile("s_waitcnt vmcnt(0)" ::: "memory");
    __builtin_amdgcn_s_barrier();
    __builtin_amdgcn_sched_barrier(0);
    cur ^= 1;
  }

  const int rbase = (lane >> 4) * 4;
#pragma unroll
  for (int m = 0; m < 4; m++) {
#pragma unroll
    for (int n = 0; n < 4; n++) {
#pragma unroll
      for (int reg = 0; reg < 4; reg++) {
        int gr = m0 + wr * 64 + m * 16 + rbase + reg;
        int gc = n0 + wc * 64 + n * 16 + (lane & 15);
        Cb[(size_t)gr * N + gc] = f2bf(fmaxf(acc[m][n][reg] + bias[gc], 0.f));
      }
    }
  }
}

// ---- split-K BN=64 GEMM for N=1024 (o-proj, FFN2), bf16 partials ----------
template <int WITH_BIAS>
__global__ __launch_bounds__(256) void gemm_nt64sk(
    const ushort* __restrict__ A, const ushort* __restrict__ B, int M, int N, int Kfull,
    int Klen, ushort* __restrict__ Cb0, ushort* __restrict__ Cb1,
    const float* __restrict__ bias) {
  __shared__ ushort As[2][128 * 32];
  __shared__ ushort Bs[2][64 * 32];
  const int t = threadIdx.x;
  const int lane = t & 63, wv = t >> 6;
  const int wr = wv >> 1, wc = wv & 1;
  const int m0 = blockIdx.y * 128, n0 = blockIdx.x * 64;
  const int z = blockIdx.z;
  const int koff = z * Klen;
  ushort* Cb = z ? Cb1 : Cb0;
  const int rif = lane & 15;
  const int kb = (lane >> 4) * 16;

  f32x4 acc[4][2] = {};
  const char* Ab = (const char*)A;
  const char* Bb = (const char*)B;
  const int arow = t >> 2;
  const int acol = (t & 3) * 16;

  auto stage = [&](int b, int k0) {
    size_t abase = ((size_t)(m0 + arow) * Kfull + koff + k0) * 2 + acol;
    gload_lds16(Ab + abase, (char*)As[b] + t * 16);
    gload_lds16(Ab + abase + (size_t)64 * Kfull * 2, (char*)As[b] + t * 16 + 4096);
    size_t bbase = ((size_t)(n0 + arow) * Kfull + koff + k0) * 2 + acol;
    gload_lds16(Bb + bbase, (char*)Bs[b] + t * 16);
  };

  stage(0, 0);
  asm volatile("s_waitcnt vmcnt(0)" ::: "memory");
  __builtin_amdgcn_s_barrier();
  __builtin_amdgcn_sched_barrier(0);

  int cur = 0;
#pragma unroll 1
  for (int k0 = 0; k0 < Klen; k0 += 32) {
    if (k0 + 32 < Klen) stage(cur ^ 1, k0 + 32);
    bf16x8 af[4], bfr[2];
#pragma unroll
    for (int m = 0; m < 4; m++)
      af[m] = *(const bf16x8*)((const char*)As[cur] + (wr * 64 + m * 16 + rif) * 64 + kb);
#pragma unroll
    for (int n = 0; n < 2; n++)
      bfr[n] = *(const bf16x8*)((const char*)Bs[cur] + (wc * 32 + n * 16 + rif) * 64 + kb);
    __builtin_amdgcn_s_setprio(1);
#pragma unroll
    for (int m = 0; m < 4; m++)
#pragma unroll
      for (int n = 0; n < 2; n++)
        acc[m][n] = __builtin_amdgcn_mfma_f32_16x16x32_bf16(af[m], bfr[n], acc[m][n], 0, 0, 0);
    __builtin_amdgcn_s_setprio(0);
    asm volatile("s_waitcnt vmcnt(0)" ::: "memory");
    __builtin_amdgcn_s_barrier();
    __builtin_amdgcn_sched_barrier(0);
    cur ^= 1;
  }

  const int rbase = (lane >> 4) * 4;
#pragma unroll
  for (int m = 0; m < 4; m++) {
#pragma unroll
    for (int n = 0; n < 2; n++) {
#pragma unroll
      for (int reg = 0; reg < 4; reg++) {
        int gr = m0 + wr * 64 + m * 16 + rbase + reg;
        int gc = n0 + wc * 32 + n * 16 + (lane & 15);
        float v = acc[m][n][reg];
        if (WITH_BIAS && z == 0) v += bias[gc];
        Cb[(size_t)gr * N + gc] = f2bf(v);
      }
    }
  }
}

// ---------------- fused causal attention (R10/R12-proven) -------------------
__global__ __launch_bounds__(256) void flash_attn(
    const ushort* __restrict__ Qw, const ushort* __restrict__ Qr,
    const ushort* __restrict__ Kb, const ushort* __restrict__ Vt,
    const ushort* __restrict__ Rk, ushort* __restrict__ out) {
  __shared__ ushort K_lds[2][64 * 64];
  __shared__ ushort V_lds[2][64 * 64];   // [d][j], swizzled
  __shared__ ushort R_lds[2][128 * 64];  // rows T0..T0+127, swizzled
  __shared__ ushort P_lds[4][16 * 64];   // per-wave P, swizzled rows

  const int t = threadIdx.x;
  const int lane = t & 63, wv = t >> 6;
  const int bn = blockIdx.y;
  const int qb = bn >> 4, hn = bn & 15;
  const int c4 = lane & 15, g4 = lane >> 4;

  const char* Qwb = (const char*)(Qw + (size_t)bn * QL * 64);
  const char* Qrb = (const char*)(Qr + (size_t)bn * QL * 64);
  const char* Kbb = (const char*)(Kb + (size_t)bn * QL * 64);
  const char* Vtb = (const char*)(Vt + (size_t)bn * 64 * QL);
  const char* Rkb = (const char*)(Rk + (size_t)hn * QL * 64);

  int addrs[4];
#pragma unroll
  for (int reg = 0; reg < 4; reg++) {
    int rr = g4 * 4 + reg;
    addrs[reg] = ((lane & 48) | ((c4 + 15 - rr) & 15)) << 2;
  }

#pragma unroll 1
  for (int ph = 0; ph < 2; ph++) {
    const int itile = (ph == 0) ? (31 - (int)blockIdx.x) : (int)blockIdx.x;
    const int i0 = itile * 64;
    const int iw = i0 + wv * 16;
    const int niter = itile + 1;

    bf16x8 qwf[2], qrf[2];
#pragma unroll
    for (int kk = 0; kk < 2; kk++) {
      qwf[kk] = *(const bf16x8*)(Qwb + (size_t)(iw + c4) * 128 + kk * 64 + g4 * 16);
      qrf[kk] = *(const bf16x8*)(Qrb + (size_t)(iw + c4) * 128 + kk * 64 + g4 * 16);
    }

    f32x4 o_acc[4] = {};
    float m_run[4], l_run[4];
#pragma unroll
    for (int r = 0; r < 4; r++) { m_run[r] = -3.0e38f; l_run[r] = 0.f; }

    auto stage = [&](int b, int j0) {
      const int T0 = j0 - i0 + (QL - 64);
#pragma unroll
      for (int p = 0; p < 2; p++) {
        int o = t * 16 + p * 4096;
        int row = o >> 7, ch16 = ((((o & 127) >> 4) ^ (row & 7)) << 4);
        gload_lds16(Kbb + (size_t)(j0 + row) * 128 + ch16, (char*)K_lds[b] + o);
        gload_lds16(Vtb + (size_t)row * (QL * 2) + (size_t)j0 * 2 + ch16, (char*)V_lds[b] + o);
      }
#pragma unroll
      for (int p = 0; p < 4; p++) {
        int o = t * 16 + p * 4096;
        int r = o >> 7;
        int srow = T0 + r; srow = srow > QL - 1 ? QL - 1 : srow;  // masked cells only
        int ch16 = ((((o & 127) >> 4) ^ (r & 7)) << 4);
        gload_lds16(Rkb + (size_t)srow * 128 + ch16, (char*)R_lds[b] + o);
      }
    };

    auto tile_body = [&](int j0, int cur, auto mc) {
      constexpr bool MASKED = decltype(mc)::value;
      f32x4 acc_s[4] = {};
      f32x4 acc_bd[5] = {};
      const int baseloc = 48 - wv * 16;
      __builtin_amdgcn_s_setprio(1);
#pragma unroll
      for (int kk = 0; kk < 2; kk++) {
        const int sw = (((kk * 4 + g4) ^ (c4 & 7)) << 4);
#pragma unroll
        for (int nf = 0; nf < 4; nf++) {
          bf16x8 bk = *(const bf16x8*)((const char*)K_lds[cur] + (nf * 16 + c4) * 128 + sw);
          acc_s[nf] = __builtin_amdgcn_mfma_f32_16x16x32_bf16(qwf[kk], bk, acc_s[nf], 0, 0, 0);
        }
#pragma unroll
        for (int tf = 0; tf < 5; tf++) {
          int oo = baseloc + tf * 16 + c4;  // oo&7 == c4&7
          bf16x8 br = *(const bf16x8*)((const char*)R_lds[cur] + oo * 128 + sw);
          acc_bd[tf] = __builtin_amdgcn_mfma_f32_16x16x32_bf16(qrf[kk], br, acc_bd[tf], 0, 0, 0);
        }
      }
      __builtin_amdgcn_s_setprio(0);

      uint32_t pk[4][4];
#pragma unroll
      for (int nf = 0; nf < 4; nf++)
#pragma unroll
        for (int reg = 0; reg < 4; reg++)
          asm("v_cvt_pk_bf16_f32 %0, %1, %2"
              : "=v"(pk[nf][reg])
              : "v"(acc_bd[nf][reg]), "v"(acc_bd[nf + 1][reg]));

      float sv[4][4];
      float rowmax[4] = {-3.0e38f, -3.0e38f, -3.0e38f, -3.0e38f};
#pragma unroll
      for (int nf = 0; nf < 4; nf++) {
#pragma unroll
        for (int reg = 0; reg < 4; reg++) {
          int rr = g4 * 4 + reg;
          uint32_t pulled = (uint32_t)__builtin_amdgcn_ds_bpermute(addrs[reg], (int)pk[nf][reg]);
          uint32_t bits = (c4 > rr) ? (pulled & 0xffff0000u) : (pulled << 16);
          float v = acc_s[nf][reg] + __uint_as_float(bits);
          if (MASKED) {
            int jg = j0 + nf * 16 + c4;
            int ig = iw + rr;
            v = (jg <= ig) ? v : -3.0e38f;
          }
          sv[nf][reg] = v;
          rowmax[reg] = fmaxf(rowmax[reg], v);
        }
      }
#pragma unroll
      for (int reg = 0; reg < 4; reg++) {
        float rm = rowmax[reg];
        rm = fmaxf(rm, __shfl_xor(rm, 1));
        rm = fmaxf(rm, __shfl_xor(rm, 2));
        rm = fmaxf(rm, __shfl_xor(rm, 4));
        rm = fmaxf(rm, __shfl_xor(rm, 8));
        float mnew = fmaxf(m_run[reg], rm);
        float alpha = __builtin_amdgcn_exp2f(m_run[reg] - mnew);
        float rsum = 0.f;
#pragma unroll
        for (int nf = 0; nf < 4; nf++) {
          float p = __builtin_amdgcn_exp2f(sv[nf][reg] - mnew);
          sv[nf][reg] = p;
          rsum += p;
        }
        rsum += __shfl_xor(rsum, 1);
        rsum += __shfl_xor(rsum, 2);
        rsum += __shfl_xor(rsum, 4);
        rsum += __shfl_xor(rsum, 8);
        l_run[reg] = l_run[reg] * alpha + rsum;
        m_run[reg] = mnew;
#pragma unroll
        for (int df = 0; df < 4; df++) o_acc[df][reg] *= alpha;
      }

      {
        char* pb = (char*)P_lds[wv];
#pragma unroll
        for (int nf = 0; nf < 4; nf++)
#pragma unroll
          for (int reg = 0; reg < 4; reg++) {
            int row = g4 * 4 + reg, col = nf * 16 + c4;
            int byt = row * 128 + ((((col >> 3) ^ (row & 7))) << 4) + (col & 7) * 2;
            *(ushort*)(pb + byt) = f2bf(sv[nf][reg]);
          }
      }
      __builtin_amdgcn_s_setprio(1);
#pragma unroll
      for (int kk = 0; kk < 2; kk++) {
        const char* pb = (const char*)P_lds[wv];
        bf16x8 pa = *(const bf16x8*)(pb + c4 * 128 + (((kk * 4 + g4) ^ (c4 & 7)) << 4));
        const int sw = (((kk * 4 + g4) ^ (c4 & 7)) << 4);
#pragma unroll
        for (int df = 0; df < 4; df++) {
          bf16x8 bv = *(const bf16x8*)((const char*)V_lds[cur] + (df * 16 + c4) * 128 + sw);
          o_acc[df] = __builtin_amdgcn_mfma_f32_16x16x32_bf16(pa, bv, o_acc[df], 0, 0, 0);
        }
      }
      __builtin_amdgcn_s_setprio(0);
    };

    stage(0, 0);
    asm volatile("s_waitcnt vmcnt(0)" ::: "memory");
    __builtin_amdgcn_s_barrier();
    __builtin_amdgcn_sched_barrier(0);

    int cur = 0;
#pragma unroll 1
    for (int it = 0; it < niter - 1; ++it) {
      stage(cur ^ 1, (it + 1) * 64);
      tile_body(it * 64, cur, BoolC<false>{});
      asm volatile("s_waitcnt vmcnt(0)" ::: "memory");
      __builtin_amdgcn_s_barrier();
      __builtin_amdgcn_sched_barrier(0);
      cur ^= 1;
    }
    tile_body(i0, cur, BoolC<true>{});
    __syncthreads();

#pragma unroll
    for (int reg = 0; reg < 4; reg++) {
      float inv = 1.0f / l_run[reg];
      int ig = iw + g4 * 4 + reg;
      size_t grow = (size_t)(ig * 2 + qb) * 1024 + hn * 64;
#pragma unroll
      for (int df = 0; df < 4; df++)
        out[grow + df * 16 + c4] = f2bf(o_acc[df][reg] * inv);
    }
  }
}

// ---- residual + 2 bf16 partials + LayerNorm.
// WF32: write f32 out; WB16: write bf16 out; XABF: residual input is bf16.
template <bool WF32, bool WB16, bool XABF>
__global__ __launch_bounds__(256) void ln_res3(
    const void* __restrict__ xa_, const ushort* __restrict__ xb0,
    const ushort* __restrict__ xb1, const float* __restrict__ g,
    const float* __restrict__ bt, float* __restrict__ of, ushort* __restrict__ ob) {
  __shared__ float red[8];
  const int row = blockIdx.x;
  const int t = threadIdx.x;
  const int lane = t & 63, wv = t >> 6;
  float a0, a1, a2, a3;
  if (XABF) {
    const ushort4 av = *(const ushort4*)((const ushort*)xa_ + (size_t)row * 1024 + t * 4);
    a0 = bf2f(av.x); a1 = bf2f(av.y); a2 = bf2f(av.z); a3 = bf2f(av.w);
  } else {
    const float4 av = *(const float4*)((const float*)xa_ + (size_t)row * 1024 + t * 4);
    a0 = av.x; a1 = av.y; a2 = av.z; a3 = av.w;
  }
  const ushort4 c0 = *(const ushort4*)(xb0 + (size_t)row * 1024 + t * 4);
  const ushort4 c1 = *(const ushort4*)(xb1 + (size_t)row * 1024 + t * 4);
  float x[4] = {a0 + bf2f(c0.x) + bf2f(c1.x), a1 + bf2f(c0.y) + bf2f(c1.y),
                a2 + bf2f(c0.z) + bf2f(c1.z), a3 + bf2f(c0.w) + bf2f(c1.w)};
  float s = x[0] + x[1] + x[2] + x[3];
  for (int m = 1; m < 64; m <<= 1) s += __shfl_xor(s, m);
  if (lane == 0) red[wv] = s;
  __syncthreads();
  float mu = (red[0] + red[1] + red[2] + red[3]) * (1.f / 1024.f);
  float d[4];
  float ss = 0.f;
#pragma unroll
  for (int i = 0; i < 4; i++) { d[i] = x[i] - mu; ss += d[i] * d[i]; }
  for (int m = 1; m < 64; m <<= 1) ss += __shfl_xor(ss, m);
  if (lane == 0) red[4 + wv] = ss;
  __syncthreads();
  float var = (red[4] + red[5] + red[6] + red[7]) * (1.f / 1024.f);
  float rs = rsqrtf(var + 1e-5f);
  float4 gv = *(const float4*)(g + t * 4);
  float4 bv = *(const float4*)(bt + t * 4);
  float y[4] = {d[0] * rs * gv.x + bv.x, d[1] * rs * gv.y + bv.y,
                d[2] * rs * gv.z + bv.z, d[3] * rs * gv.w + bv.w};
  if (WF32) {
    float4 yo = make_float4(y[0], y[1], y[2], y[3]);
    *(float4*)(of + (size_t)row * 1024 + t * 4) = yo;
  }
  if (WB16) {
    ushort4 u;
    u.x = f2bf(y[0]); u.y = f2bf(y[1]); u.z = f2bf(y[2]); u.w = f2bf(y[3]);
    *(ushort4*)(ob + (size_t)row * 1024 + t * 4) = u;
  }
}

// ---------------- host orchestration ----------------
extern "C" void kernel_launch(void* const* d_in, const int* in_sizes, int n_in,
                              void* d_out, int out_size, void* d_ws, size_t ws_size,
                              hipStream_t stream) {
  const float* dec_inp = (const float*)d_in[0];
  const float* r_in = (const float*)d_in[1];
  const float* rwb = (const float*)d_in[2];
  const float* rrb = (const float*)d_in[3];
  const float* qkv_w = (const float*)d_in[4];
  const float* rnet_w = (const float*)d_in[5];
  const float* o_w = (const float*)d_in[6];
  const float* ln_attn_g = (const float*)d_in[7];
  const float* ln_attn_b = (const float*)d_in[8];
  const float* w1 = (const float*)d_in[9];
  const float* b1 = (const float*)d_in[10];
  const float* w2 = (const float*)d_in[11];
  const float* b2 = (const float*)d_in[12];
  const float* ln_ff_g = (const float*)d_in[13];
  const float* ln_ff_b = (const float*)d_in[14];
  float* out = (float*)d_out;

  char* ws = (char*)d_ws;
  size_t off = 0;
  auto alloc = [&](size_t bytes) {
    char* p = ws + off;
    off += (bytes + 255) & ~(size_t)255;
    return p;
  };
  const int ROWS = QL * 2;
  ushort* qkvw_b = (ushort*)alloc((size_t)3072 * 1024 * 2);
  ushort* rnetw_b = (ushort*)alloc((size_t)1024 * 1024 * 2);
  ushort* ow_b = (ushort*)alloc((size_t)1024 * 1024 * 2);
  ushort* w1_b = (ushort*)alloc((size_t)4096 * 1024 * 2);
  ushort* w2_b = (ushort*)alloc((size_t)1024 * 4096 * 2);
  ushort* x_b = (ushort*)alloc((size_t)ROWS * 1024 * 2);
  ushort* r_b = (ushort*)alloc((size_t)QL * 1024 * 2);
  ushort* Qw = (ushort*)alloc((size_t)32 * QL * 64 * 2);
  ushort* Qr = (ushort*)alloc((size_t)32 * QL * 64 * 2);
  ushort* Kb = (ushort*)alloc((size_t)32 * QL * 64 * 2);
  ushort* Vt = (ushort*)alloc((size_t)32 * 64 * QL * 2);
  ushort* rk = (ushort*)alloc((size_t)16 * QL * 64 * 2);
  ushort* avec = (ushort*)alloc((size_t)ROWS * 1024 * 2);
  ushort* p0 = (ushort*)alloc((size_t)ROWS * 1024 * 2);
  ushort* p1 = (ushort*)alloc((size_t)ROWS * 1024 * 2);
  ushort* x1b = (ushort*)alloc((size_t)ROWS * 1024 * 2);
  ushort* hidden = (ushort*)alloc((size_t)ROWS * 4096 * 2);
  ushort* q0 = (ushort*)alloc((size_t)ROWS * 1024 * 2);
  ushort* q1 = (ushort*)alloc((size_t)ROWS * 1024 * 2);

  // critical-path conversions: qkv_w, rnet_w, dec_inp, r
  CvtArgs ca;
  {
    int n4[4] = {3072 * 1024 / 4, 1024 * 1024 / 4, ROWS * 1024 / 4, QL * 1024 / 4};
    const float* srcs[4] = {qkv_w, rnet_w, dec_inp, r_in};
    ushort* dsts[4] = {qkvw_b, rnetw_b, x_b, r_b};
    int cum = 0;
    for (int i = 0; i < 4; i++) {
      ca.src[i] = srcs[i];
      ca.dst[i] = dsts[i];
      cum += n4[i];
      ca.end[i] = cum;
    }
    cvt_all_k<<<2048, 256, 0, stream>>>(ca, cum);
  }

  // fat dispatch: QKV proj + rk proj + deferred cvt of o_w/w1/w2
  Cvt3 cv;
  int cvt_total4;
  {
    int n4[3] = {1024 * 1024 / 4, 4096 * 1024 / 4, 1024 * 4096 / 4};
    const float* srcs[3] = {o_w, w1, w2};
    ushort* dsts[3] = {ow_b, w1_b, w2_b};
    int cum = 0;
    for (int i = 0; i < 3; i++) {
      cv.src[i] = srcs[i];
      cv.dst[i] = dsts[i];
      cum += n4[i];
      cv.end[i] = cum;
    }
    cvt_total4 = cum;
  }
  fat_qkv_rk_cvt<<<1792, 256, 0, stream>>>(x_b, qkvw_b, r_b, rnetw_b, Qw, Qr, Kb, Vt, rk,
                                           rwb, rrb, cv, cvt_total4);

  flash_attn<<<dim3(16, 32), 256, 0, stream>>>(Qw, Qr, Kb, Vt, rk, avec);
  // o-proj split-K=2 (K=512 each), bf16 partials p0/p1
  gemm_nt64sk<0><<<dim3(1024 / 64, ROWS / 128, 2), 256, 0, stream>>>(
      avec, ow_b, ROWS, 1024, 1024, 512, p0, p1, nullptr);
  // post-LN 1: residual dec_inp (f32) + p0 + p1 -> x1b (bf16 only; x1f dropped)
  ln_res3<false, true, false><<<ROWS, 256, 0, stream>>>(
      dec_inp, p0, p1, ln_attn_g, ln_attn_b, nullptr, x1b);
  gemm_ffn1<<<dim3(4096 / 128, ROWS / 128), 256, 0, stream>>>(
      x1b, w1_b, ROWS, 4096, 1024, hidden, b1);
  // FFN2 split-K=2 (K=2048 each), bias folded into z==0 partial
  gemm_nt64sk<1><<<dim3(1024 / 64, ROWS / 128, 2), 256, 0, stream>>>(
      hidden, w2_b, ROWS, 1024, 4096, 2048, q0, q1, b2);
  // post-LN 2: residual x1b (bf16) + q0 + q1 -> out (f32)
  ln_res3<true, false, true><<<ROWS, 256, 0, stream>>>(
      x1b, q0, q1, ln_ff_g, ln_ff_b, out, nullptr);
}

// Round 16
// 324.621 us; speedup vs baseline: 1.3482x; 1.0013x over previous
//
#include <hip/hip_runtime.h>
#include <stdint.h>

#define QL 2048
#define NHEAD 16
#define DHEAD 64
#define DMODEL 1024
#define DINNER 4096

typedef __attribute__((ext_vector_type(8))) short bf16x8;
typedef __attribute__((ext_vector_type(4))) float f32x4;

template <bool V>
struct BoolC { static constexpr bool value = V; };

__device__ __forceinline__ ushort f2bf(float f) {
  uint32_t u = __float_as_uint(f);
  u = (u + 0x7fffu + ((u >> 16) & 1u)) >> 16;
  return (ushort)u;
}
__device__ __forceinline__ float bf2f(ushort u) {
  return __uint_as_float(((uint32_t)u) << 16);
}

__device__ __forceinline__ void gload_lds16(const void* g, void* l) {
  auto gp = reinterpret_cast<const uint32_t __attribute__((address_space(1)))*>(
      reinterpret_cast<uintptr_t>(g));
  auto lp = reinterpret_cast<uint32_t __attribute__((address_space(3)))*>(
      (uint32_t)reinterpret_cast<uintptr_t>(l));
  __builtin_amdgcn_global_load_lds(gp, lp, 16, 0, 0);
}

// softmax scale folded into Q at projection: 0.125 * log2(e)
#define QSCALE 0.18033688011112042f

// ---------------- fp32 -> bf16 conversion (4 critical-path buffers) ----------
struct CvtArgs {
  const float* src[4];
  ushort* dst[4];
  int end[4];  // cumulative float4 counts
};

__global__ __launch_bounds__(256) void cvt_all_k(CvtArgs a, int total4) {
  for (int i = blockIdx.x * 256 + threadIdx.x; i < total4; i += gridDim.x * 256) {
    int seg = 0;
#pragma unroll
    for (int s = 0; s < 3; s++)
      if (i >= a.end[s]) seg = s + 1;
    int base = seg ? a.end[seg - 1] : 0;
    int j = i - base;
    float4 v = ((const float4*)a.src[seg])[j];
    ushort4 u;
    u.x = f2bf(v.x); u.y = f2bf(v.y); u.z = f2bf(v.z); u.w = f2bf(v.w);
    ((ushort4*)a.dst[seg])[j] = u;
  }
}

// ---- fat dispatch #1: QKV(768 blocks) + rk(512) + deferred cvt(512) --------
struct Cvt3 {
  const float* src[3];
  ushort* dst[3];
  int end[3];
};

__global__ __launch_bounds__(256) void fat_qkv_rk_cvt(
    const ushort* __restrict__ xb, const ushort* __restrict__ qkvw,
    const ushort* __restrict__ rb, const ushort* __restrict__ rnetw,
    ushort* __restrict__ qw, ushort* __restrict__ qr, ushort* __restrict__ kbuf,
    ushort* __restrict__ vt, ushort* __restrict__ rkout,
    const float* __restrict__ rwb, const float* __restrict__ rrb,
    Cvt3 cv, int cvt_total4) {
  __shared__ char smem[32768];
  const int bid = blockIdx.x;
  const int t = threadIdx.x;
  const int lane = t & 63, wv = t >> 6;
  const int wr = wv >> 1, wc = wv & 1;
  const int rif = lane & 15;
  const int kb = (lane >> 4) * 16;
  const int arow = t >> 2;
  const int acol = (t & 3) * 16;
  const int rbase = (lane >> 4) * 4;

  if (bid < 768) {
    // ---------- QKV: C[4096,3072] = xb × qkvw^T, 128² tile, 2-phase ----------
    const int bx = bid % 24, by = bid / 24;
    const int m0 = by * 128, n0 = bx * 128;
    const int K = 1024;
    const char* Ab = (const char*)xb;
    const char* Bb = (const char*)qkvw;

    f32x4 acc[4][4] = {};
    auto stage = [&](int b, int k0) {
      char* As = smem + b * 8192;
      char* Bs = smem + 16384 + b * 8192;
      size_t abase = ((size_t)(m0 + arow) * K + k0) * 2 + acol;
      gload_lds16(Ab + abase, As + t * 16);
      gload_lds16(Ab + abase + (size_t)64 * K * 2, As + t * 16 + 4096);
      size_t bbase = ((size_t)(n0 + arow) * K + k0) * 2 + acol;
      gload_lds16(Bb + bbase, Bs + t * 16);
      gload_lds16(Bb + bbase + (size_t)64 * K * 2, Bs + t * 16 + 4096);
    };

    stage(0, 0);
    asm volatile("s_waitcnt vmcnt(0)" ::: "memory");
    __builtin_amdgcn_s_barrier();
    __builtin_amdgcn_sched_barrier(0);

    int cur = 0;
#pragma unroll 1
    for (int k0 = 0; k0 < K; k0 += 32) {
      if (k0 + 32 < K) stage(cur ^ 1, k0 + 32);
      const char* As = smem + cur * 8192;
      const char* Bs = smem + 16384 + cur * 8192;
      bf16x8 af[4], bfr[4];
#pragma unroll
      for (int m = 0; m < 4; m++)
        af[m] = *(const bf16x8*)(As + (wr * 64 + m * 16 + rif) * 64 + kb);
#pragma unroll
      for (int n = 0; n < 4; n++)
        bfr[n] = *(const bf16x8*)(Bs + (wc * 64 + n * 16 + rif) * 64 + kb);
      __builtin_amdgcn_s_setprio(1);
#pragma unroll
      for (int m = 0; m < 4; m++)
#pragma unroll
        for (int n = 0; n < 4; n++)
          acc[m][n] = __builtin_amdgcn_mfma_f32_16x16x32_bf16(af[m], bfr[n], acc[m][n], 0, 0, 0);
      __builtin_amdgcn_s_setprio(0);
      asm volatile("s_waitcnt vmcnt(0)" ::: "memory");
      __builtin_amdgcn_s_barrier();
      __builtin_amdgcn_sched_barrier(0);
      cur ^= 1;
    }

#pragma unroll
    for (int m = 0; m < 4; m++) {
#pragma unroll
      for (int n = 0; n < 4; n++) {
#pragma unroll
        for (int reg = 0; reg < 4; reg++) {
          int gr = m0 + wr * 64 + m * 16 + rbase + reg;
          int gc = n0 + wc * 64 + n * 16 + (lane & 15);
          float v = acc[m][n][reg];
          int which = gc >> 10, hh = gc & 1023;
          int hn = hh >> 6, hd = hh & 63;
          int qi = gr >> 1, qb = gr & 1;
          size_t off = ((size_t)(qb * NHEAD + hn) * QL + qi) * 64 + hd;
          if (which == 0) {
            qw[off] = f2bf((v + rwb[hh]) * QSCALE);
            qr[off] = f2bf((v + rrb[hh]) * QSCALE);
          } else if (which == 1) {
            kbuf[off] = f2bf(v);
          } else {
            vt[((size_t)(qb * NHEAD + hn) * 64 + hd) * QL + qi] = f2bf(v);
          }
        }
      }
    }
  } else if (bid < 1280) {
    // ---------- rk: rkout = rb[2048,1024] × rnetw^T, 64² tile, 2-phase -------
    const int b = bid - 768;
    const int bx = b % 16, by = b / 16;
    const int m0 = by * 64, n0 = bx * 64;
    const int K = 1024;
    const char* Ab = (const char*)rb;
    const char* Bb = (const char*)rnetw;

    f32x4 acc[2][2] = {};
    auto stage = [&](int bb, int k0) {
      char* As = smem + bb * 4096;
      char* Bs = smem + 8192 + bb * 4096;
      size_t abase = ((size_t)(m0 + arow) * K + k0) * 2 + acol;
      gload_lds16(Ab + abase, As + t * 16);
      size_t bbase = ((size_t)(n0 + arow) * K + k0) * 2 + acol;
      gload_lds16(Bb + bbase, Bs + t * 16);
    };

    stage(0, 0);
    asm volatile("s_waitcnt vmcnt(0)" ::: "memory");
    __builtin_amdgcn_s_barrier();
    __builtin_amdgcn_sched_barrier(0);

    int cur = 0;
#pragma unroll 1
    for (int k0 = 0; k0 < K; k0 += 32) {
      if (k0 + 32 < K) stage(cur ^ 1, k0 + 32);
      const char* As = smem + cur * 4096;
      const char* Bs = smem + 8192 + cur * 4096;
      bf16x8 af[2], bfr[2];
#pragma unroll
      for (int m = 0; m < 2; m++)
        af[m] = *(const bf16x8*)(As + (wr * 32 + m * 16 + rif) * 64 + kb);
#pragma unroll
      for (int n = 0; n < 2; n++)
        bfr[n] = *(const bf16x8*)(Bs + (wc * 32 + n * 16 + rif) * 64 + kb);
      __builtin_amdgcn_s_setprio(1);
#pragma unroll
      for (int m = 0; m < 2; m++)
#pragma unroll
        for (int n = 0; n < 2; n++)
          acc[m][n] = __builtin_amdgcn_mfma_f32_16x16x32_bf16(af[m], bfr[n], acc[m][n], 0, 0, 0);
      __builtin_amdgcn_s_setprio(0);
      asm volatile("s_waitcnt vmcnt(0)" ::: "memory");
      __builtin_amdgcn_s_barrier();
      __builtin_amdgcn_sched_barrier(0);
      cur ^= 1;
    }

#pragma unroll
    for (int m = 0; m < 2; m++) {
#pragma unroll
      for (int n = 0; n < 2; n++) {
#pragma unroll
        for (int reg = 0; reg < 4; reg++) {
          int gr = m0 + wr * 32 + m * 16 + rbase + reg;
          int gc = n0 + wc * 32 + n * 16 + (lane & 15);
          int hn = gc >> 6, hd = gc & 63;
          rkout[((size_t)hn * QL + gr) * 64 + hd] = f2bf(acc[m][n][reg]);
        }
      }
    }
  } else {
    // ---------- deferred cvt of o_w, w1, w2 (not needed until after flash) ---
    for (int i = (bid - 1280) * 256 + t; i < cvt_total4; i += 512 * 256) {
      int seg = 0;
#pragma unroll
      for (int s = 0; s < 2; s++)
        if (i >= cv.end[s]) seg = s + 1;
      int base = seg ? cv.end[seg - 1] : 0;
      int j = i - base;
      float4 v = ((const float4*)cv.src[seg])[j];
      ushort4 u;
      u.x = f2bf(v.x); u.y = f2bf(v.y); u.z = f2bf(v.z); u.w = f2bf(v.w);
      ((ushort4*)cv.dst[seg])[j] = u;
    }
  }
}

// ---------------- FFN1 GEMM (R8-proven 2-phase, bias+relu+bf16) -------------
__global__ __launch_bounds__(256) void gemm_ffn1(
    const ushort* __restrict__ A, const ushort* __restrict__ B, int M, int N, int K,
    ushort* __restrict__ Cb, const float* __restrict__ bias) {
  __shared__ ushort As[2][128 * 32];
  __shared__ ushort Bs[2][128 * 32];
  const int t = threadIdx.x;
  const int lane = t & 63, wv = t >> 6;
  const int wr = wv >> 1, wc = wv & 1;
  const int m0 = blockIdx.y * 128, n0 = blockIdx.x * 128;
  const int rif = lane & 15;
  const int kb = (lane >> 4) * 16;

  f32x4 acc[4][4] = {};
  const char* Ab = (const char*)A;
  const char* Bb = (const char*)B;
  const int arow = t >> 2;
  const int acol = (t & 3) * 16;

  auto stage = [&](int b, int k0) {
    size_t abase = ((size_t)(m0 + arow) * K + k0) * 2 + acol;
    gload_lds16(Ab + abase, (char*)As[b] + t * 16);
    gload_lds16(Ab + abase + (size_t)64 * K * 2, (char*)As[b] + t * 16 + 4096);
    size_t bbase = ((size_t)(n0 + arow) * K + k0) * 2 + acol;
    gload_lds16(Bb + bbase, (char*)Bs[b] + t * 16);
    gload_lds16(Bb + bbase + (size_t)64 * K * 2, (char*)Bs[b] + t * 16 + 4096);
  };

  stage(0, 0);
  asm volatile("s_waitcnt vmcnt(0)" ::: "memory");
  __builtin_amdgcn_s_barrier();
  __builtin_amdgcn_sched_barrier(0);

  int cur = 0;
#pragma unroll 1
  for (int k0 = 0; k0 < K; k0 += 32) {
    if (k0 + 32 < K) stage(cur ^ 1, k0 + 32);
    bf16x8 af[4], bfr[4];
#pragma unroll
    for (int m = 0; m < 4; m++)
      af[m] = *(const bf16x8*)((const char*)As[cur] + (wr * 64 + m * 16 + rif) * 64 + kb);
#pragma unroll
    for (int n = 0; n < 4; n++)
      bfr[n] = *(const bf16x8*)((const char*)Bs[cur] + (wc * 64 + n * 16 + rif) * 64 + kb);
    __builtin_amdgcn_s_setprio(1);
#pragma unroll
    for (int m = 0; m < 4; m++)
#pragma unroll
      for (int n = 0; n < 4; n++)
        acc[m][n] = __builtin_amdgcn_mfma_f32_16x16x32_bf16(af[m], bfr[n], acc[m][n], 0, 0, 0);
    __builtin_amdgcn_s_setprio(0);
    asm volatile("s_waitcnt vmcnt(0)" ::: "memory");
    __builtin_amdgcn_s_barrier();
    __builtin_amdgcn_sched_barrier(0);
    cur ^= 1;
  }

  const int rbase = (lane >> 4) * 4;
#pragma unroll
  for (int m = 0; m < 4; m++) {
#pragma unroll
    for (int n = 0; n < 4; n++) {
#pragma unroll
      for (int reg = 0; reg < 4; reg++) {
        int gr = m0 + wr * 64 + m * 16 + rbase + reg;
        int gc = n0 + wc * 64 + n * 16 + (lane & 15);
        Cb[(size_t)gr * N + gc] = f2bf(fmaxf(acc[m][n][reg] + bias[gc], 0.f));
      }
    }
  }
}

// ---- split-K BN=64 GEMM for N=1024 (o-proj, FFN2), bf16 partials ----------
template <int WITH_BIAS>
__global__ __launch_bounds__(256) void gemm_nt64sk(
    const ushort* __restrict__ A, const ushort* __restrict__ B, int M, int N, int Kfull,
    int Klen, ushort* __restrict__ Cb0, ushort* __restrict__ Cb1,
    const float* __restrict__ bias) {
  __shared__ ushort As[2][128 * 32];
  __shared__ ushort Bs[2][64 * 32];
  const int t = threadIdx.x;
  const int lane = t & 63, wv = t >> 6;
  const int wr = wv >> 1, wc = wv & 1;
  const int m0 = blockIdx.y * 128, n0 = blockIdx.x * 64;
  const int z = blockIdx.z;
  const int koff = z * Klen;
  ushort* Cb = z ? Cb1 : Cb0;
  const int rif = lane & 15;
  const int kb = (lane >> 4) * 16;

  f32x4 acc[4][2] = {};
  const char* Ab = (const char*)A;
  const char* Bb = (const char*)B;
  const int arow = t >> 2;
  const int acol = (t & 3) * 16;

  auto stage = [&](int b, int k0) {
    size_t abase = ((size_t)(m0 + arow) * Kfull + koff + k0) * 2 + acol;
    gload_lds16(Ab + abase, (char*)As[b] + t * 16);
    gload_lds16(Ab + abase + (size_t)64 * Kfull * 2, (char*)As[b] + t * 16 + 4096);
    size_t bbase = ((size_t)(n0 + arow) * Kfull + koff + k0) * 2 + acol;
    gload_lds16(Bb + bbase, (char*)Bs[b] + t * 16);
  };

  stage(0, 0);
  asm volatile("s_waitcnt vmcnt(0)" ::: "memory");
  __builtin_amdgcn_s_barrier();
  __builtin_amdgcn_sched_barrier(0);

  int cur = 0;
#pragma unroll 1
  for (int k0 = 0; k0 < Klen; k0 += 32) {
    if (k0 + 32 < Klen) stage(cur ^ 1, k0 + 32);
    bf16x8 af[4], bfr[2];
#pragma unroll
    for (int m = 0; m < 4; m++)
      af[m] = *(const bf16x8*)((const char*)As[cur] + (wr * 64 + m * 16 + rif) * 64 + kb);
#pragma unroll
    for (int n = 0; n < 2; n++)
      bfr[n] = *(const bf16x8*)((const char*)Bs[cur] + (wc * 32 + n * 16 + rif) * 64 + kb);
    __builtin_amdgcn_s_setprio(1);
#pragma unroll
    for (int m = 0; m < 4; m++)
#pragma unroll
      for (int n = 0; n < 2; n++)
        acc[m][n] = __builtin_amdgcn_mfma_f32_16x16x32_bf16(af[m], bfr[n], acc[m][n], 0, 0, 0);
    __builtin_amdgcn_s_setprio(0);
    asm volatile("s_waitcnt vmcnt(0)" ::: "memory");
    __builtin_amdgcn_s_barrier();
    __builtin_amdgcn_sched_barrier(0);
    cur ^= 1;
  }

  const int rbase = (lane >> 4) * 4;
#pragma unroll
  for (int m = 0; m < 4; m++) {
#pragma unroll
    for (int n = 0; n < 2; n++) {
#pragma unroll
      for (int reg = 0; reg < 4; reg++) {
        int gr = m0 + wr * 64 + m * 16 + rbase + reg;
        int gc = n0 + wc * 32 + n * 16 + (lane & 15);
        float v = acc[m][n][reg];
        if (WITH_BIAS && z == 0) v += bias[gc];
        Cb[(size_t)gr * N + gc] = f2bf(v);
      }
    }
  }
}

// ---------------- fused causal attention (R12 + T13 defer-max) --------------
__global__ __launch_bounds__(256) void flash_attn(
    const ushort* __restrict__ Qw, const ushort* __restrict__ Qr,
    const ushort* __restrict__ Kb, const ushort* __restrict__ Vt,
    const ushort* __restrict__ Rk, ushort* __restrict__ out) {
  __shared__ ushort K_lds[2][64 * 64];
  __shared__ ushort V_lds[2][64 * 64];   // [d][j], swizzled
  __shared__ ushort R_lds[2][128 * 64];  // rows T0..T0+127, swizzled
  __shared__ ushort P_lds[4][16 * 64];   // per-wave P, swizzled rows

  const int t = threadIdx.x;
  const int lane = t & 63, wv = t >> 6;
  const int bn = blockIdx.y;
  const int qb = bn >> 4, hn = bn & 15;
  const int c4 = lane & 15, g4 = lane >> 4;

  const char* Qwb = (const char*)(Qw + (size_t)bn * QL * 64);
  const char* Qrb = (const char*)(Qr + (size_t)bn * QL * 64);
  const char* Kbb = (const char*)(Kb + (size_t)bn * QL * 64);
  const char* Vtb = (const char*)(Vt + (size_t)bn * 64 * QL);
  const char* Rkb = (const char*)(Rk + (size_t)hn * QL * 64);

  int addrs[4];
#pragma unroll
  for (int reg = 0; reg < 4; reg++) {
    int rr = g4 * 4 + reg;
    addrs[reg] = ((lane & 48) | ((c4 + 15 - rr) & 15)) << 2;
  }

#pragma unroll 1
  for (int ph = 0; ph < 2; ph++) {
    const int itile = (ph == 0) ? (31 - (int)blockIdx.x) : (int)blockIdx.x;
    const int i0 = itile * 64;
    const int iw = i0 + wv * 16;
    const int niter = itile + 1;

    bf16x8 qwf[2], qrf[2];
#pragma unroll
    for (int kk = 0; kk < 2; kk++) {
      qwf[kk] = *(const bf16x8*)(Qwb + (size_t)(iw + c4) * 128 + kk * 64 + g4 * 16);
      qrf[kk] = *(const bf16x8*)(Qrb + (size_t)(iw + c4) * 128 + kk * 64 + g4 * 16);
    }

    f32x4 o_acc[4] = {};
    float m_run[4], l_run[4];
#pragma unroll
    for (int r = 0; r < 4; r++) { m_run[r] = -3.0e38f; l_run[r] = 0.f; }

    auto stage = [&](int b, int j0) {
      const int T0 = j0 - i0 + (QL - 64);
#pragma unroll
      for (int p = 0; p < 2; p++) {
        int o = t * 16 + p * 4096;
        int row = o >> 7, ch16 = ((((o & 127) >> 4) ^ (row & 7)) << 4);
        gload_lds16(Kbb + (size_t)(j0 + row) * 128 + ch16, (char*)K_lds[b] + o);
        gload_lds16(Vtb + (size_t)row * (QL * 2) + (size_t)j0 * 2 + ch16, (char*)V_lds[b] + o);
      }
#pragma unroll
      for (int p = 0; p < 4; p++) {
        int o = t * 16 + p * 4096;
        int r = o >> 7;
        int srow = T0 + r; srow = srow > QL - 1 ? QL - 1 : srow;  // masked cells only
        int ch16 = ((((o & 127) >> 4) ^ (r & 7)) << 4);
        gload_lds16(Rkb + (size_t)srow * 128 + ch16, (char*)R_lds[b] + o);
      }
    };

    auto tile_body = [&](int j0, int cur, auto mc) {
      constexpr bool MASKED = decltype(mc)::value;
      f32x4 acc_s[4] = {};
      f32x4 acc_bd[5] = {};
      const int baseloc = 48 - wv * 16;
      __builtin_amdgcn_s_setprio(1);
#pragma unroll
      for (int kk = 0; kk < 2; kk++) {
        const int sw = (((kk * 4 + g4) ^ (c4 & 7)) << 4);
#pragma unroll
        for (int nf = 0; nf < 4; nf++) {
          bf16x8 bk = *(const bf16x8*)((const char*)K_lds[cur] + (nf * 16 + c4) * 128 + sw);
          acc_s[nf] = __builtin_amdgcn_mfma_f32_16x16x32_bf16(qwf[kk], bk, acc_s[nf], 0, 0, 0);
        }
#pragma unroll
        for (int tf = 0; tf < 5; tf++) {
          int oo = baseloc + tf * 16 + c4;  // oo&7 == c4&7
          bf16x8 br = *(const bf16x8*)((const char*)R_lds[cur] + oo * 128 + sw);
          acc_bd[tf] = __builtin_amdgcn_mfma_f32_16x16x32_bf16(qrf[kk], br, acc_bd[tf], 0, 0, 0);
        }
      }
      __builtin_amdgcn_s_setprio(0);

      uint32_t pk[4][4];
#pragma unroll
      for (int nf = 0; nf < 4; nf++)
#pragma unroll
        for (int reg = 0; reg < 4; reg++)
          asm("v_cvt_pk_bf16_f32 %0, %1, %2"
              : "=v"(pk[nf][reg])
              : "v"(acc_bd[nf][reg]), "v"(acc_bd[nf + 1][reg]));

      float sv[4][4];
      float rowmax[4] = {-3.0e38f, -3.0e38f, -3.0e38f, -3.0e38f};
#pragma unroll
      for (int nf = 0; nf < 4; nf++) {
#pragma unroll
        for (int reg = 0; reg < 4; reg++) {
          int rr = g4 * 4 + reg;
          uint32_t pulled = (uint32_t)__builtin_amdgcn_ds_bpermute(addrs[reg], (int)pk[nf][reg]);
          uint32_t bits = (c4 > rr) ? (pulled & 0xffff0000u) : (pulled << 16);
          float v = acc_s[nf][reg] + __uint_as_float(bits);
          if (MASKED) {
            int jg = j0 + nf * 16 + c4;
            int ig = iw + rr;
            v = (jg <= ig) ? v : -3.0e38f;
          }
          sv[nf][reg] = v;
          rowmax[reg] = fmaxf(rowmax[reg], v);
        }
      }
      // T13 defer-max: skip O/l rescale when per-wave max growth <= 8 (log2)
      float rmv[4];
      int need = 0;
#pragma unroll
      for (int reg = 0; reg < 4; reg++) {
        float rm = rowmax[reg];
        rm = fmaxf(rm, __shfl_xor(rm, 1));
        rm = fmaxf(rm, __shfl_xor(rm, 2));
        rm = fmaxf(rm, __shfl_xor(rm, 4));
        rm = fmaxf(rm, __shfl_xor(rm, 8));
        rmv[reg] = rm;
        need |= (rm > m_run[reg] + 8.0f) ? 1 : 0;
      }
      if (!__all(need == 0)) {
#pragma unroll
        for (int reg = 0; reg < 4; reg++) {
          float mnew = fmaxf(m_run[reg], rmv[reg]);
          float alpha = __builtin_amdgcn_exp2f(m_run[reg] - mnew);
          l_run[reg] *= alpha;
          m_run[reg] = mnew;
#pragma unroll
          for (int df = 0; df < 4; df++) o_acc[df][reg] *= alpha;
        }
      }
#pragma unroll
      for (int reg = 0; reg < 4; reg++) {
        float rsum = 0.f;
#pragma unroll
        for (int nf = 0; nf < 4; nf++) {
          float p = __builtin_amdgcn_exp2f(sv[nf][reg] - m_run[reg]);
          sv[nf][reg] = p;
          rsum += p;
        }
        rsum += __shfl_xor(rsum, 1);
        rsum += __shfl_xor(rsum, 2);
        rsum += __shfl_xor(rsum, 4);
        rsum += __shfl_xor(rsum, 8);
        l_run[reg] += rsum;
      }

      {
        char* pb = (char*)P_lds[wv];
#pragma unroll
        for (int nf = 0; nf < 4; nf++)
#pragma unroll
          for (int reg = 0; reg < 4; reg++) {
            int row = g4 * 4 + reg, col = nf * 16 + c4;
            int byt = row * 128 + ((((col >> 3) ^ (row & 7))) << 4) + (col & 7) * 2;
            *(ushort*)(pb + byt) = f2bf(sv[nf][reg]);
          }
      }
      __builtin_amdgcn_s_setprio(1);
#pragma unroll
      for (int kk = 0; kk < 2; kk++) {
        const char* pb = (const char*)P_lds[wv];
        bf16x8 pa = *(const bf16x8*)(pb + c4 * 128 + (((kk * 4 + g4) ^ (c4 & 7)) << 4));
        const int sw = (((kk * 4 + g4) ^ (c4 & 7)) << 4);
#pragma unroll
        for (int df = 0; df < 4; df++) {
          bf16x8 bv = *(const bf16x8*)((const char*)V_lds[cur] + (df * 16 + c4) * 128 + sw);
          o_acc[df] = __builtin_amdgcn_mfma_f32_16x16x32_bf16(pa, bv, o_acc[df], 0, 0, 0);
        }
      }
      __builtin_amdgcn_s_setprio(0);
    };

    stage(0, 0);
    asm volatile("s_waitcnt vmcnt(0)" ::: "memory");
    __builtin_amdgcn_s_barrier();
    __builtin_amdgcn_sched_barrier(0);

    int cur = 0;
#pragma unroll 1
    for (int it = 0; it < niter - 1; ++it) {
      stage(cur ^ 1, (it + 1) * 64);
      tile_body(it * 64, cur, BoolC<false>{});
      asm volatile("s_waitcnt vmcnt(0)" ::: "memory");
      __builtin_amdgcn_s_barrier();
      __builtin_amdgcn_sched_barrier(0);
      cur ^= 1;
    }
    tile_body(i0, cur, BoolC<true>{});
    __syncthreads();

#pragma unroll
    for (int reg = 0; reg < 4; reg++) {
      float inv = 1.0f / l_run[reg];
      int ig = iw + g4 * 4 + reg;
      size_t grow = (size_t)(ig * 2 + qb) * 1024 + hn * 64;
#pragma unroll
      for (int df = 0; df < 4; df++)
        out[grow + df * 16 + c4] = f2bf(o_acc[df][reg] * inv);
    }
  }
}

// ---- residual + 2 bf16 partials + LayerNorm.
// WF32: write f32 out; WB16: write bf16 out; XABF: residual input is bf16.
template <bool WF32, bool WB16, bool XABF>
__global__ __launch_bounds__(256) void ln_res3(
    const void* __restrict__ xa_, const ushort* __restrict__ xb0,
    const ushort* __restrict__ xb1, const float* __restrict__ g,
    const float* __restrict__ bt, float* __restrict__ of, ushort* __restrict__ ob) {
  __shared__ float red[8];
  const int row = blockIdx.x;
  const int t = threadIdx.x;
  const int lane = t & 63, wv = t >> 6;
  float a0, a1, a2, a3;
  if (XABF) {
    const ushort4 av = *(const ushort4*)((const ushort*)xa_ + (size_t)row * 1024 + t * 4);
    a0 = bf2f(av.x); a1 = bf2f(av.y); a2 = bf2f(av.z); a3 = bf2f(av.w);
  } else {
    const float4 av = *(const float4*)((const float*)xa_ + (size_t)row * 1024 + t * 4);
    a0 = av.x; a1 = av.y; a2 = av.z; a3 = av.w;
  }
  const ushort4 c0 = *(const ushort4*)(xb0 + (size_t)row * 1024 + t * 4);
  const ushort4 c1 = *(const ushort4*)(xb1 + (size_t)row * 1024 + t * 4);
  float x[4] = {a0 + bf2f(c0.x) + bf2f(c1.x), a1 + bf2f(c0.y) + bf2f(c1.y),
                a2 + bf2f(c0.z) + bf2f(c1.z), a3 + bf2f(c0.w) + bf2f(c1.w)};
  float s = x[0] + x[1] + x[2] + x[3];
  for (int m = 1; m < 64; m <<= 1) s += __shfl_xor(s, m);
  if (lane == 0) red[wv] = s;
  __syncthreads();
  float mu = (red[0] + red[1] + red[2] + red[3]) * (1.f / 1024.f);
  float d[4];
  float ss = 0.f;
#pragma unroll
  for (int i = 0; i < 4; i++) { d[i] = x[i] - mu; ss += d[i] * d[i]; }
  for (int m = 1; m < 64; m <<= 1) ss += __shfl_xor(ss, m);
  if (lane == 0) red[4 + wv] = ss;
  __syncthreads();
  float var = (red[4] + red[5] + red[6] + red[7]) * (1.f / 1024.f);
  float rs = rsqrtf(var + 1e-5f);
  float4 gv = *(const float4*)(g + t * 4);
  float4 bv = *(const float4*)(bt + t * 4);
  float y[4] = {d[0] * rs * gv.x + bv.x, d[1] * rs * gv.y + bv.y,
                d[2] * rs * gv.z + bv.z, d[3] * rs * gv.w + bv.w};
  if (WF32) {
    float4 yo = make_float4(y[0], y[1], y[2], y[3]);
    *(float4*)(of + (size_t)row * 1024 + t * 4) = yo;
  }
  if (WB16) {
    ushort4 u;
    u.x = f2bf(y[0]); u.y = f2bf(y[1]); u.z = f2bf(y[2]); u.w = f2bf(y[3]);
    *(ushort4*)(ob + (size_t)row * 1024 + t * 4) = u;
  }
}

// ---------------- host orchestration ----------------
extern "C" void kernel_launch(void* const* d_in, const int* in_sizes, int n_in,
                              void* d_out, int out_size, void* d_ws, size_t ws_size,
                              hipStream_t stream) {
  const float* dec_inp = (const float*)d_in[0];
  const float* r_in = (const float*)d_in[1];
  const float* rwb = (const float*)d_in[2];
  const float* rrb = (const float*)d_in[3];
  const float* qkv_w = (const float*)d_in[4];
  const float* rnet_w = (const float*)d_in[5];
  const float* o_w = (const float*)d_in[6];
  const float* ln_attn_g = (const float*)d_in[7];
  const float* ln_attn_b = (const float*)d_in[8];
  const float* w1 = (const float*)d_in[9];
  const float* b1 = (const float*)d_in[10];
  const float* w2 = (const float*)d_in[11];
  const float* b2 = (const float*)d_in[12];
  const float* ln_ff_g = (const float*)d_in[13];
  const float* ln_ff_b = (const float*)d_in[14];
  float* out = (float*)d_out;

  char* ws = (char*)d_ws;
  size_t off = 0;
  auto alloc = [&](size_t bytes) {
    char* p = ws + off;
    off += (bytes + 255) & ~(size_t)255;
    return p;
  };
  const int ROWS = QL * 2;
  ushort* qkvw_b = (ushort*)alloc((size_t)3072 * 1024 * 2);
  ushort* rnetw_b = (ushort*)alloc((size_t)1024 * 1024 * 2);
  ushort* ow_b = (ushort*)alloc((size_t)1024 * 1024 * 2);
  ushort* w1_b = (ushort*)alloc((size_t)4096 * 1024 * 2);
  ushort* w2_b = (ushort*)alloc((size_t)1024 * 4096 * 2);
  ushort* x_b = (ushort*)alloc((size_t)ROWS * 1024 * 2);
  ushort* r_b = (ushort*)alloc((size_t)QL * 1024 * 2);
  ushort* Qw = (ushort*)alloc((size_t)32 * QL * 64 * 2);
  ushort* Qr = (ushort*)alloc((size_t)32 * QL * 64 * 2);
  ushort* Kb = (ushort*)alloc((size_t)32 * QL * 64 * 2);
  ushort* Vt = (ushort*)alloc((size_t)32 * 64 * QL * 2);
  ushort* rk = (ushort*)alloc((size_t)16 * QL * 64 * 2);
  ushort* avec = (ushort*)alloc((size_t)ROWS * 1024 * 2);
  ushort* p0 = (ushort*)alloc((size_t)ROWS * 1024 * 2);
  ushort* p1 = (ushort*)alloc((size_t)ROWS * 1024 * 2);
  ushort* x1b = (ushort*)alloc((size_t)ROWS * 1024 * 2);
  ushort* hidden = (ushort*)alloc((size_t)ROWS * 4096 * 2);
  ushort* q0 = (ushort*)alloc((size_t)ROWS * 1024 * 2);
  ushort* q1 = (ushort*)alloc((size_t)ROWS * 1024 * 2);

  // critical-path conversions: qkv_w, rnet_w, dec_inp, r
  CvtArgs ca;
  {
    int n4[4] = {3072 * 1024 / 4, 1024 * 1024 / 4, ROWS * 1024 / 4, QL * 1024 / 4};
    const float* srcs[4] = {qkv_w, rnet_w, dec_inp, r_in};
    ushort* dsts[4] = {qkvw_b, rnetw_b, x_b, r_b};
    int cum = 0;
    for (int i = 0; i < 4; i++) {
      ca.src[i] = srcs[i];
      ca.dst[i] = dsts[i];
      cum += n4[i];
      ca.end[i] = cum;
    }
    cvt_all_k<<<2048, 256, 0, stream>>>(ca, cum);
  }

  // fat dispatch: QKV proj + rk proj + deferred cvt of o_w/w1/w2
  Cvt3 cv;
  int cvt_total4;
  {
    int n4[3] = {1024 * 1024 / 4, 4096 * 1024 / 4, 1024 * 4096 / 4};
    const float* srcs[3] = {o_w, w1, w2};
    ushort* dsts[3] = {ow_b, w1_b, w2_b};
    int cum = 0;
    for (int i = 0; i < 3; i++) {
      cv.src[i] = srcs[i];
      cv.dst[i] = dsts[i];
      cum += n4[i];
      cv.end[i] = cum;
    }
    cvt_total4 = cum;
  }
  fat_qkv_rk_cvt<<<1792, 256, 0, stream>>>(x_b, qkvw_b, r_b, rnetw_b, Qw, Qr, Kb, Vt, rk,
                                           rwb, rrb, cv, cvt_total4);

  flash_attn<<<dim3(16, 32), 256, 0, stream>>>(Qw, Qr, Kb, Vt, rk, avec);
  // o-proj split-K=2 (K=512 each), bf16 partials p0/p1
  gemm_nt64sk<0><<<dim3(1024 / 64, ROWS / 128, 2), 256, 0, stream>>>(
      avec, ow_b, ROWS, 1024, 1024, 512, p0, p1, nullptr);
  // post-LN 1: residual dec_inp (f32) + p0 + p1 -> x1b (bf16 only)
  ln_res3<false, true, false><<<ROWS, 256, 0, stream>>>(
      dec_inp, p0, p1, ln_attn_g, ln_attn_b, nullptr, x1b);
  gemm_ffn1<<<dim3(4096 / 128, ROWS / 128), 256, 0, stream>>>(
      x1b, w1_b, ROWS, 4096, 1024, hidden, b1);
  // FFN2 split-K=2 (K=2048 each), bias folded into z==0 partial
  gemm_nt64sk<1><<<dim3(1024 / 64, ROWS / 128, 2), 256, 0, stream>>>(
      hidden, w2_b, ROWS, 1024, 4096, 2048, q0, q1, b2);
  // post-LN 2: residual x1b (bf16) + q0 + q1 -> out (f32)
  ln_res3<true, false, true><<<ROWS, 256, 0, stream>>>(
      x1b, q0, q1, ln_ff_g, ln_ff_b, out, nullptr);
}

// Round 17
// 323.848 us; speedup vs baseline: 1.3514x; 1.0024x over previous
//
#include <hip/hip_runtime.h>
#include <stdint.h>

#define QL 2048
#define NHEAD 16
#define DHEAD 64
#define DMODEL 1024
#define DINNER 4096

typedef __attribute__((ext_vector_type(8))) short bf16x8;
typedef __attribute__((ext_vector_type(4))) float f32x4;

template <bool V>
struct BoolC { static constexpr bool value = V; };

__device__ __forceinline__ ushort f2bf(float f) {
  uint32_t u = __float_as_uint(f);
  u = (u + 0x7fffu + ((u >> 16) & 1u)) >> 16;
  return (ushort)u;
}
__device__ __forceinline__ float bf2f(ushort u) {
  return __uint_as_float(((uint32_t)u) << 16);
}

__device__ __forceinline__ void gload_lds16(const void* g, void* l) {
  auto gp = reinterpret_cast<const uint32_t __attribute__((address_space(1)))*>(
      reinterpret_cast<uintptr_t>(g));
  auto lp = reinterpret_cast<uint32_t __attribute__((address_space(3)))*>(
      (uint32_t)reinterpret_cast<uintptr_t>(l));
  __builtin_amdgcn_global_load_lds(gp, lp, 16, 0, 0);
}

// softmax scale folded into Q at projection: 0.125 * log2(e)
#define QSCALE 0.18033688011112042f

// ---------------- fp32 -> bf16 conversion (4 critical-path buffers) ----------
struct CvtArgs {
  const float* src[4];
  ushort* dst[4];
  int end[4];  // cumulative float4 counts
};

__global__ __launch_bounds__(256) void cvt_all_k(CvtArgs a, int total4) {
  for (int i = blockIdx.x * 256 + threadIdx.x; i < total4; i += gridDim.x * 256) {
    int seg = 0;
#pragma unroll
    for (int s = 0; s < 3; s++)
      if (i >= a.end[s]) seg = s + 1;
    int base = seg ? a.end[seg - 1] : 0;
    int j = i - base;
    float4 v = ((const float4*)a.src[seg])[j];
    ushort4 u;
    u.x = f2bf(v.x); u.y = f2bf(v.y); u.z = f2bf(v.z); u.w = f2bf(v.w);
    ((ushort4*)a.dst[seg])[j] = u;
  }
}

// ---- fat dispatch #1: QKV(768 blocks) + rk(512) + deferred cvt(512) --------
struct Cvt3 {
  const float* src[3];
  ushort* dst[3];
  int end[3];
};

__global__ __launch_bounds__(256) void fat_qkv_rk_cvt(
    const ushort* __restrict__ xb, const ushort* __restrict__ qkvw,
    const ushort* __restrict__ rb, const ushort* __restrict__ rnetw,
    ushort* __restrict__ qw, ushort* __restrict__ qr, ushort* __restrict__ kbuf,
    ushort* __restrict__ vt, ushort* __restrict__ rkout,
    const float* __restrict__ rwb, const float* __restrict__ rrb,
    Cvt3 cv, int cvt_total4) {
  __shared__ char smem[32768];
  const int bid = blockIdx.x;
  const int t = threadIdx.x;
  const int lane = t & 63, wv = t >> 6;
  const int wr = wv >> 1, wc = wv & 1;
  const int rif = lane & 15;
  const int kb = (lane >> 4) * 16;
  const int arow = t >> 2;
  const int acol = (t & 3) * 16;
  const int rbase = (lane >> 4) * 4;

  if (bid < 768) {
    // ---------- QKV: C[4096,3072] = xb × qkvw^T, 128² tile, 2-phase ----------
    const int bx = bid % 24, by = bid / 24;
    const int m0 = by * 128, n0 = bx * 128;
    const int K = 1024;
    const char* Ab = (const char*)xb;
    const char* Bb = (const char*)qkvw;

    f32x4 acc[4][4] = {};
    auto stage = [&](int b, int k0) {
      char* As = smem + b * 8192;
      char* Bs = smem + 16384 + b * 8192;
      size_t abase = ((size_t)(m0 + arow) * K + k0) * 2 + acol;
      gload_lds16(Ab + abase, As + t * 16);
      gload_lds16(Ab + abase + (size_t)64 * K * 2, As + t * 16 + 4096);
      size_t bbase = ((size_t)(n0 + arow) * K + k0) * 2 + acol;
      gload_lds16(Bb + bbase, Bs + t * 16);
      gload_lds16(Bb + bbase + (size_t)64 * K * 2, Bs + t * 16 + 4096);
    };

    stage(0, 0);
    asm volatile("s_waitcnt vmcnt(0)" ::: "memory");
    __builtin_amdgcn_s_barrier();
    __builtin_amdgcn_sched_barrier(0);

    int cur = 0;
#pragma unroll 1
    for (int k0 = 0; k0 < K; k0 += 32) {
      if (k0 + 32 < K) stage(cur ^ 1, k0 + 32);
      const char* As = smem + cur * 8192;
      const char* Bs = smem + 16384 + cur * 8192;
      bf16x8 af[4], bfr[4];
#pragma unroll
      for (int m = 0; m < 4; m++)
        af[m] = *(const bf16x8*)(As + (wr * 64 + m * 16 + rif) * 64 + kb);
#pragma unroll
      for (int n = 0; n < 4; n++)
        bfr[n] = *(const bf16x8*)(Bs + (wc * 64 + n * 16 + rif) * 64 + kb);
      __builtin_amdgcn_s_setprio(1);
#pragma unroll
      for (int m = 0; m < 4; m++)
#pragma unroll
        for (int n = 0; n < 4; n++)
          acc[m][n] = __builtin_amdgcn_mfma_f32_16x16x32_bf16(af[m], bfr[n], acc[m][n], 0, 0, 0);
      __builtin_amdgcn_s_setprio(0);
      asm volatile("s_waitcnt vmcnt(0)" ::: "memory");
      __builtin_amdgcn_s_barrier();
      __builtin_amdgcn_sched_barrier(0);
      cur ^= 1;
    }

#pragma unroll
    for (int m = 0; m < 4; m++) {
#pragma unroll
      for (int n = 0; n < 4; n++) {
#pragma unroll
        for (int reg = 0; reg < 4; reg++) {
          int gr = m0 + wr * 64 + m * 16 + rbase + reg;
          int gc = n0 + wc * 64 + n * 16 + (lane & 15);
          float v = acc[m][n][reg];
          int which = gc >> 10, hh = gc & 1023;
          int hn = hh >> 6, hd = hh & 63;
          int qi = gr >> 1, qb = gr & 1;
          size_t off = ((size_t)(qb * NHEAD + hn) * QL + qi) * 64 + hd;
          if (which == 0) {
            qw[off] = f2bf((v + rwb[hh]) * QSCALE);
            qr[off] = f2bf((v + rrb[hh]) * QSCALE);
          } else if (which == 1) {
            kbuf[off] = f2bf(v);
          } else {
            vt[((size_t)(qb * NHEAD + hn) * 64 + hd) * QL + qi] = f2bf(v);
          }
        }
      }
    }
  } else if (bid < 1280) {
    // ---------- rk: rkout = rb[2048,1024] × rnetw^T, 64² tile, 2-phase -------
    const int b = bid - 768;
    const int bx = b % 16, by = b / 16;
    const int m0 = by * 64, n0 = bx * 64;
    const int K = 1024;
    const char* Ab = (const char*)rb;
    const char* Bb = (const char*)rnetw;

    f32x4 acc[2][2] = {};
    auto stage = [&](int bb, int k0) {
      char* As = smem + bb * 4096;
      char* Bs = smem + 8192 + bb * 4096;
      size_t abase = ((size_t)(m0 + arow) * K + k0) * 2 + acol;
      gload_lds16(Ab + abase, As + t * 16);
      size_t bbase = ((size_t)(n0 + arow) * K + k0) * 2 + acol;
      gload_lds16(Bb + bbase, Bs + t * 16);
    };

    stage(0, 0);
    asm volatile("s_waitcnt vmcnt(0)" ::: "memory");
    __builtin_amdgcn_s_barrier();
    __builtin_amdgcn_sched_barrier(0);

    int cur = 0;
#pragma unroll 1
    for (int k0 = 0; k0 < K; k0 += 32) {
      if (k0 + 32 < K) stage(cur ^ 1, k0 + 32);
      const char* As = smem + cur * 4096;
      const char* Bs = smem + 8192 + cur * 4096;
      bf16x8 af[2], bfr[2];
#pragma unroll
      for (int m = 0; m < 2; m++)
        af[m] = *(const bf16x8*)(As + (wr * 32 + m * 16 + rif) * 64 + kb);
#pragma unroll
      for (int n = 0; n < 2; n++)
        bfr[n] = *(const bf16x8*)(Bs + (wc * 32 + n * 16 + rif) * 64 + kb);
      __builtin_amdgcn_s_setprio(1);
#pragma unroll
      for (int m = 0; m < 2; m++)
#pragma unroll
        for (int n = 0; n < 2; n++)
          acc[m][n] = __builtin_amdgcn_mfma_f32_16x16x32_bf16(af[m], bfr[n], acc[m][n], 0, 0, 0);
      __builtin_amdgcn_s_setprio(0);
      asm volatile("s_waitcnt vmcnt(0)" ::: "memory");
      __builtin_amdgcn_s_barrier();
      __builtin_amdgcn_sched_barrier(0);
      cur ^= 1;
    }

#pragma unroll
    for (int m = 0; m < 2; m++) {
#pragma unroll
      for (int n = 0; n < 2; n++) {
#pragma unroll
        for (int reg = 0; reg < 4; reg++) {
          int gr = m0 + wr * 32 + m * 16 + rbase + reg;
          int gc = n0 + wc * 32 + n * 16 + (lane & 15);
          int hn = gc >> 6, hd = gc & 63;
          rkout[((size_t)hn * QL + gr) * 64 + hd] = f2bf(acc[m][n][reg]);
        }
      }
    }
  } else {
    // ---------- deferred cvt of o_w, w1, w2 (not needed until after flash) ---
    for (int i = (bid - 1280) * 256 + t; i < cvt_total4; i += 512 * 256) {
      int seg = 0;
#pragma unroll
      for (int s = 0; s < 2; s++)
        if (i >= cv.end[s]) seg = s + 1;
      int base = seg ? cv.end[seg - 1] : 0;
      int j = i - base;
      float4 v = ((const float4*)cv.src[seg])[j];
      ushort4 u;
      u.x = f2bf(v.x); u.y = f2bf(v.y); u.z = f2bf(v.z); u.w = f2bf(v.w);
      ((ushort4*)cv.dst[seg])[j] = u;
    }
  }
}

// ---------------- FFN1 GEMM (R8-proven 2-phase, bias+relu+bf16) -------------
__global__ __launch_bounds__(256) void gemm_ffn1(
    const ushort* __restrict__ A, const ushort* __restrict__ B, int M, int N, int K,
    ushort* __restrict__ Cb, const float* __restrict__ bias) {
  __shared__ ushort As[2][128 * 32];
  __shared__ ushort Bs[2][128 * 32];
  const int t = threadIdx.x;
  const int lane = t & 63, wv = t >> 6;
  const int wr = wv >> 1, wc = wv & 1;
  const int m0 = blockIdx.y * 128, n0 = blockIdx.x * 128;
  const int rif = lane & 15;
  const int kb = (lane >> 4) * 16;

  f32x4 acc[4][4] = {};
  const char* Ab = (const char*)A;
  const char* Bb = (const char*)B;
  const int arow = t >> 2;
  const int acol = (t & 3) * 16;

  auto stage = [&](int b, int k0) {
    size_t abase = ((size_t)(m0 + arow) * K + k0) * 2 + acol;
    gload_lds16(Ab + abase, (char*)As[b] + t * 16);
    gload_lds16(Ab + abase + (size_t)64 * K * 2, (char*)As[b] + t * 16 + 4096);
    size_t bbase = ((size_t)(n0 + arow) * K + k0) * 2 + acol;
    gload_lds16(Bb + bbase, (char*)Bs[b] + t * 16);
    gload_lds16(Bb + bbase + (size_t)64 * K * 2, (char*)Bs[b] + t * 16 + 4096);
  };

  stage(0, 0);
  asm volatile("s_waitcnt vmcnt(0)" ::: "memory");
  __builtin_amdgcn_s_barrier();
  __builtin_amdgcn_sched_barrier(0);

  int cur = 0;
#pragma unroll 1
  for (int k0 = 0; k0 < K; k0 += 32) {
    if (k0 + 32 < K) stage(cur ^ 1, k0 + 32);
    bf16x8 af[4], bfr[4];
#pragma unroll
    for (int m = 0; m < 4; m++)
      af[m] = *(const bf16x8*)((const char*)As[cur] + (wr * 64 + m * 16 + rif) * 64 + kb);
#pragma unroll
    for (int n = 0; n < 4; n++)
      bfr[n] = *(const bf16x8*)((const char*)Bs[cur] + (wc * 64 + n * 16 + rif) * 64 + kb);
    __builtin_amdgcn_s_setprio(1);
#pragma unroll
    for (int m = 0; m < 4; m++)
#pragma unroll
      for (int n = 0; n < 4; n++)
        acc[m][n] = __builtin_amdgcn_mfma_f32_16x16x32_bf16(af[m], bfr[n], acc[m][n], 0, 0, 0);
    __builtin_amdgcn_s_setprio(0);
    asm volatile("s_waitcnt vmcnt(0)" ::: "memory");
    __builtin_amdgcn_s_barrier();
    __builtin_amdgcn_sched_barrier(0);
    cur ^= 1;
  }

  const int rbase = (lane >> 4) * 4;
#pragma unroll
  for (int m = 0; m < 4; m++) {
#pragma unroll
    for (int n = 0; n < 4; n++) {
#pragma unroll
      for (int reg = 0; reg < 4; reg++) {
        int gr = m0 + wr * 64 + m * 16 + rbase + reg;
        int gc = n0 + wc * 64 + n * 16 + (lane & 15);
        Cb[(size_t)gr * N + gc] = f2bf(fmaxf(acc[m][n][reg] + bias[gc], 0.f));
      }
    }
  }
}

// ---- split-K BN=64 GEMM for N=1024 (o-proj, FFN2), bf16 partials ----------
template <int WITH_BIAS>
__global__ __launch_bounds__(256) void gemm_nt64sk(
    const ushort* __restrict__ A, const ushort* __restrict__ B, int M, int N, int Kfull,
    int Klen, ushort* __restrict__ Cb0, ushort* __restrict__ Cb1,
    const float* __restrict__ bias) {
  __shared__ ushort As[2][128 * 32];
  __shared__ ushort Bs[2][64 * 32];
  const int t = threadIdx.x;
  const int lane = t & 63, wv = t >> 6;
  const int wr = wv >> 1, wc = wv & 1;
  const int m0 = blockIdx.y * 128, n0 = blockIdx.x * 64;
  const int z = blockIdx.z;
  const int koff = z * Klen;
  ushort* Cb = z ? Cb1 : Cb0;
  const int rif = lane & 15;
  const int kb = (lane >> 4) * 16;

  f32x4 acc[4][2] = {};
  const char* Ab = (const char*)A;
  const char* Bb = (const char*)B;
  const int arow = t >> 2;
  const int acol = (t & 3) * 16;

  auto stage = [&](int b, int k0) {
    size_t abase = ((size_t)(m0 + arow) * Kfull + koff + k0) * 2 + acol;
    gload_lds16(Ab + abase, (char*)As[b] + t * 16);
    gload_lds16(Ab + abase + (size_t)64 * Kfull * 2, (char*)As[b] + t * 16 + 4096);
    size_t bbase = ((size_t)(n0 + arow) * Kfull + koff + k0) * 2 + acol;
    gload_lds16(Bb + bbase, (char*)Bs[b] + t * 16);
  };

  stage(0, 0);
  asm volatile("s_waitcnt vmcnt(0)" ::: "memory");
  __builtin_amdgcn_s_barrier();
  __builtin_amdgcn_sched_barrier(0);

  int cur = 0;
#pragma unroll 1
  for (int k0 = 0; k0 < Klen; k0 += 32) {
    if (k0 + 32 < Klen) stage(cur ^ 1, k0 + 32);
    bf16x8 af[4], bfr[2];
#pragma unroll
    for (int m = 0; m < 4; m++)
      af[m] = *(const bf16x8*)((const char*)As[cur] + (wr * 64 + m * 16 + rif) * 64 + kb);
#pragma unroll
    for (int n = 0; n < 2; n++)
      bfr[n] = *(const bf16x8*)((const char*)Bs[cur] + (wc * 32 + n * 16 + rif) * 64 + kb);
    __builtin_amdgcn_s_setprio(1);
#pragma unroll
    for (int m = 0; m < 4; m++)
#pragma unroll
      for (int n = 0; n < 2; n++)
        acc[m][n] = __builtin_amdgcn_mfma_f32_16x16x32_bf16(af[m], bfr[n], acc[m][n], 0, 0, 0);
    __builtin_amdgcn_s_setprio(0);
    asm volatile("s_waitcnt vmcnt(0)" ::: "memory");
    __builtin_amdgcn_s_barrier();
    __builtin_amdgcn_sched_barrier(0);
    cur ^= 1;
  }

  const int rbase = (lane >> 4) * 4;
#pragma unroll
  for (int m = 0; m < 4; m++) {
#pragma unroll
    for (int n = 0; n < 2; n++) {
#pragma unroll
      for (int reg = 0; reg < 4; reg++) {
        int gr = m0 + wr * 64 + m * 16 + rbase + reg;
        int gc = n0 + wc * 32 + n * 16 + (lane & 15);
        float v = acc[m][n][reg];
        if (WITH_BIAS && z == 0) v += bias[gc];
        Cb[(size_t)gr * N + gc] = f2bf(v);
      }
    }
  }
}

// ---- fused causal attention (R16 + cross-phase prefetch of ph1 tile 0) -----
__global__ __launch_bounds__(256) void flash_attn(
    const ushort* __restrict__ Qw, const ushort* __restrict__ Qr,
    const ushort* __restrict__ Kb, const ushort* __restrict__ Vt,
    const ushort* __restrict__ Rk, ushort* __restrict__ out) {
  __shared__ ushort K_lds[2][64 * 64];
  __shared__ ushort V_lds[2][64 * 64];   // [d][j], swizzled
  __shared__ ushort R_lds[2][128 * 64];  // rows T0..T0+127, swizzled
  __shared__ ushort P_lds[4][16 * 64];   // per-wave P, swizzled rows

  const int t = threadIdx.x;
  const int lane = t & 63, wv = t >> 6;
  const int bn = blockIdx.y;
  const int qb = bn >> 4, hn = bn & 15;
  const int c4 = lane & 15, g4 = lane >> 4;

  const char* Qwb = (const char*)(Qw + (size_t)bn * QL * 64);
  const char* Qrb = (const char*)(Qr + (size_t)bn * QL * 64);
  const char* Kbb = (const char*)(Kb + (size_t)bn * QL * 64);
  const char* Vtb = (const char*)(Vt + (size_t)bn * 64 * QL);
  const char* Rkb = (const char*)(Rk + (size_t)hn * QL * 64);

  int addrs[4];
#pragma unroll
  for (int reg = 0; reg < 4; reg++) {
    int rr = g4 * 4 + reg;
    addrs[reg] = ((lane & 48) | ((c4 + 15 - rr) & 15)) << 2;
  }

  // stage K,V tile j0 and R window for a given i0 into buffer b
  auto stage = [&](int b, int j0, int i0) {
    const int T0 = j0 - i0 + (QL - 64);
#pragma unroll
    for (int p = 0; p < 2; p++) {
      int o = t * 16 + p * 4096;
      int row = o >> 7, ch16 = ((((o & 127) >> 4) ^ (row & 7)) << 4);
      gload_lds16(Kbb + (size_t)(j0 + row) * 128 + ch16, (char*)K_lds[b] + o);
      gload_lds16(Vtb + (size_t)row * (QL * 2) + (size_t)j0 * 2 + ch16, (char*)V_lds[b] + o);
    }
#pragma unroll
    for (int p = 0; p < 4; p++) {
      int o = t * 16 + p * 4096;
      int r = o >> 7;
      int srow = T0 + r; srow = srow > QL - 1 ? QL - 1 : srow;  // masked cells only
      int ch16 = ((((o & 127) >> 4) ^ (r & 7)) << 4);
      gload_lds16(Rkb + (size_t)srow * 128 + ch16, (char*)R_lds[b] + o);
    }
  };

  int cur = 0;
  {
    const int itile0 = 31 - (int)blockIdx.x;
    stage(0, 0, itile0 * 64);  // global prologue (ph0, tile 0)
    asm volatile("s_waitcnt vmcnt(0)" ::: "memory");
    __builtin_amdgcn_s_barrier();
    __builtin_amdgcn_sched_barrier(0);
  }

#pragma unroll 1
  for (int ph = 0; ph < 2; ph++) {
    const int itile = (ph == 0) ? (31 - (int)blockIdx.x) : (int)blockIdx.x;
    const int i0 = itile * 64;
    const int iw = i0 + wv * 16;
    const int niter = itile + 1;
    // next phase's first tile (prefetched during this phase's diagonal)
    const int itile_n = (ph == 0) ? (int)blockIdx.x : -1;

    bf16x8 qwf[2], qrf[2];
#pragma unroll
    for (int kk = 0; kk < 2; kk++) {
      qwf[kk] = *(const bf16x8*)(Qwb + (size_t)(iw + c4) * 128 + kk * 64 + g4 * 16);
      qrf[kk] = *(const bf16x8*)(Qrb + (size_t)(iw + c4) * 128 + kk * 64 + g4 * 16);
    }

    f32x4 o_acc[4] = {};
    float m_run[4], l_run[4];
#pragma unroll
    for (int r = 0; r < 4; r++) { m_run[r] = -3.0e38f; l_run[r] = 0.f; }

    auto tile_body = [&](int j0, int cb, auto mc) {
      constexpr bool MASKED = decltype(mc)::value;
      f32x4 acc_s[4] = {};
      f32x4 acc_bd[5] = {};
      const int baseloc = 48 - wv * 16;
      __builtin_amdgcn_s_setprio(1);
#pragma unroll
      for (int kk = 0; kk < 2; kk++) {
        const int sw = (((kk * 4 + g4) ^ (c4 & 7)) << 4);
#pragma unroll
        for (int nf = 0; nf < 4; nf++) {
          bf16x8 bk = *(const bf16x8*)((const char*)K_lds[cb] + (nf * 16 + c4) * 128 + sw);
          acc_s[nf] = __builtin_amdgcn_mfma_f32_16x16x32_bf16(qwf[kk], bk, acc_s[nf], 0, 0, 0);
        }
#pragma unroll
        for (int tf = 0; tf < 5; tf++) {
          int oo = baseloc + tf * 16 + c4;  // oo&7 == c4&7
          bf16x8 br = *(const bf16x8*)((const char*)R_lds[cb] + oo * 128 + sw);
          acc_bd[tf] = __builtin_amdgcn_mfma_f32_16x16x32_bf16(qrf[kk], br, acc_bd[tf], 0, 0, 0);
        }
      }
      __builtin_amdgcn_s_setprio(0);

      uint32_t pk[4][4];
#pragma unroll
      for (int nf = 0; nf < 4; nf++)
#pragma unroll
        for (int reg = 0; reg < 4; reg++)
          asm("v_cvt_pk_bf16_f32 %0, %1, %2"
              : "=v"(pk[nf][reg])
              : "v"(acc_bd[nf][reg]), "v"(acc_bd[nf + 1][reg]));

      float sv[4][4];
      float rowmax[4] = {-3.0e38f, -3.0e38f, -3.0e38f, -3.0e38f};
#pragma unroll
      for (int nf = 0; nf < 4; nf++) {
#pragma unroll
        for (int reg = 0; reg < 4; reg++) {
          int rr = g4 * 4 + reg;
          uint32_t pulled = (uint32_t)__builtin_amdgcn_ds_bpermute(addrs[reg], (int)pk[nf][reg]);
          uint32_t bits = (c4 > rr) ? (pulled & 0xffff0000u) : (pulled << 16);
          float v = acc_s[nf][reg] + __uint_as_float(bits);
          if (MASKED) {
            int jg = j0 + nf * 16 + c4;
            int ig = iw + rr;
            v = (jg <= ig) ? v : -3.0e38f;
          }
          sv[nf][reg] = v;
          rowmax[reg] = fmaxf(rowmax[reg], v);
        }
      }
      // T13 defer-max: skip O/l rescale when per-wave max growth <= 8 (log2)
      float rmv[4];
      int need = 0;
#pragma unroll
      for (int reg = 0; reg < 4; reg++) {
        float rm = rowmax[reg];
        rm = fmaxf(rm, __shfl_xor(rm, 1));
        rm = fmaxf(rm, __shfl_xor(rm, 2));
        rm = fmaxf(rm, __shfl_xor(rm, 4));
        rm = fmaxf(rm, __shfl_xor(rm, 8));
        rmv[reg] = rm;
        need |= (rm > m_run[reg] + 8.0f) ? 1 : 0;
      }
      if (!__all(need == 0)) {
#pragma unroll
        for (int reg = 0; reg < 4; reg++) {
          float mnew = fmaxf(m_run[reg], rmv[reg]);
          float alpha = __builtin_amdgcn_exp2f(m_run[reg] - mnew);
          l_run[reg] *= alpha;
          m_run[reg] = mnew;
#pragma unroll
          for (int df = 0; df < 4; df++) o_acc[df][reg] *= alpha;
        }
      }
#pragma unroll
      for (int reg = 0; reg < 4; reg++) {
        float rsum = 0.f;
#pragma unroll
        for (int nf = 0; nf < 4; nf++) {
          float p = __builtin_amdgcn_exp2f(sv[nf][reg] - m_run[reg]);
          sv[nf][reg] = p;
          rsum += p;
        }
        rsum += __shfl_xor(rsum, 1);
        rsum += __shfl_xor(rsum, 2);
        rsum += __shfl_xor(rsum, 4);
        rsum += __shfl_xor(rsum, 8);
        l_run[reg] += rsum;
      }

      {
        char* pb = (char*)P_lds[wv];
#pragma unroll
        for (int nf = 0; nf < 4; nf++)
#pragma unroll
          for (int reg = 0; reg < 4; reg++) {
            int row = g4 * 4 + reg, col = nf * 16 + c4;
            int byt = row * 128 + ((((col >> 3) ^ (row & 7))) << 4) + (col & 7) * 2;
            *(ushort*)(pb + byt) = f2bf(sv[nf][reg]);
          }
      }
      __builtin_amdgcn_s_setprio(1);
#pragma unroll
      for (int kk = 0; kk < 2; kk++) {
        const char* pb = (const char*)P_lds[wv];
        bf16x8 pa = *(const bf16x8*)(pb + c4 * 128 + (((kk * 4 + g4) ^ (c4 & 7)) << 4));
        const int sw = (((kk * 4 + g4) ^ (c4 & 7)) << 4);
#pragma unroll
        for (int df = 0; df < 4; df++) {
          bf16x8 bv = *(const bf16x8*)((const char*)V_lds[cb] + (df * 16 + c4) * 128 + sw);
          o_acc[df] = __builtin_amdgcn_mfma_f32_16x16x32_bf16(pa, bv, o_acc[df], 0, 0, 0);
        }
      }
      __builtin_amdgcn_s_setprio(0);
    };

#pragma unroll 1
    for (int it = 0; it < niter - 1; ++it) {
      stage(cur ^ 1, (it + 1) * 64, i0);
      tile_body(it * 64, cur, BoolC<false>{});
      asm volatile("s_waitcnt vmcnt(0)" ::: "memory");
      __builtin_amdgcn_s_barrier();
      __builtin_amdgcn_sched_barrier(0);
      cur ^= 1;
    }
    // diagonal tile: no same-phase staging -> prefetch next phase's tile 0.
    // buf[cur^1]'s last readers all passed the preceding barrier (main-loop
    // invariant), so the overwrite is race-free; the drain below covers it.
    if (itile_n >= 0) stage(cur ^ 1, 0, itile_n * 64);
    tile_body(i0, cur, BoolC<true>{});
    asm volatile("s_waitcnt vmcnt(0)" ::: "memory");
    __builtin_amdgcn_s_barrier();
    __builtin_amdgcn_sched_barrier(0);
    cur ^= 1;

#pragma unroll
    for (int reg = 0; reg < 4; reg++) {
      float inv = 1.0f / l_run[reg];
      int ig = iw + g4 * 4 + reg;
      size_t grow = (size_t)(ig * 2 + qb) * 1024 + hn * 64;
#pragma unroll
      for (int df = 0; df < 4; df++)
        out[grow + df * 16 + c4] = f2bf(o_acc[df][reg] * inv);
    }
  }
}

// ---- residual + 2 bf16 partials + LayerNorm.
// WF32: write f32 out; WB16: write bf16 out; XABF: residual input is bf16.
template <bool WF32, bool WB16, bool XABF>
__global__ __launch_bounds__(256) void ln_res3(
    const void* __restrict__ xa_, const ushort* __restrict__ xb0,
    const ushort* __restrict__ xb1, const float* __restrict__ g,
    const float* __restrict__ bt, float* __restrict__ of, ushort* __restrict__ ob) {
  __shared__ float red[8];
  const int row = blockIdx.x;
  const int t = threadIdx.x;
  const int lane = t & 63, wv = t >> 6;
  float a0, a1, a2, a3;
  if (XABF) {
    const ushort4 av = *(const ushort4*)((const ushort*)xa_ + (size_t)row * 1024 + t * 4);
    a0 = bf2f(av.x); a1 = bf2f(av.y); a2 = bf2f(av.z); a3 = bf2f(av.w);
  } else {
    const float4 av = *(const float4*)((const float*)xa_ + (size_t)row * 1024 + t * 4);
    a0 = av.x; a1 = av.y; a2 = av.z; a3 = av.w;
  }
  const ushort4 c0 = *(const ushort4*)(xb0 + (size_t)row * 1024 + t * 4);
  const ushort4 c1 = *(const ushort4*)(xb1 + (size_t)row * 1024 + t * 4);
  float x[4] = {a0 + bf2f(c0.x) + bf2f(c1.x), a1 + bf2f(c0.y) + bf2f(c1.y),
                a2 + bf2f(c0.z) + bf2f(c1.z), a3 + bf2f(c0.w) + bf2f(c1.w)};
  float s = x[0] + x[1] + x[2] + x[3];
  for (int m = 1; m < 64; m <<= 1) s += __shfl_xor(s, m);
  if (lane == 0) red[wv] = s;
  __syncthreads();
  float mu = (red[0] + red[1] + red[2] + red[3]) * (1.f / 1024.f);
  float d[4];
  float ss = 0.f;
#pragma unroll
  for (int i = 0; i < 4; i++) { d[i] = x[i] - mu; ss += d[i] * d[i]; }
  for (int m = 1; m < 64; m <<= 1) ss += __shfl_xor(ss, m);
  if (lane == 0) red[4 + wv] = ss;
  __syncthreads();
  float var = (red[4] + red[5] + red[6] + red[7]) * (1.f / 1024.f);
  float rs = rsqrtf(var + 1e-5f);
  float4 gv = *(const float4*)(g + t * 4);
  float4 bv = *(const float4*)(bt + t * 4);
  float y[4] = {d[0] * rs * gv.x + bv.x, d[1] * rs * gv.y + bv.y,
                d[2] * rs * gv.z + bv.z, d[3] * rs * gv.w + bv.w};
  if (WF32) {
    float4 yo = make_float4(y[0], y[1], y[2], y[3]);
    *(float4*)(of + (size_t)row * 1024 + t * 4) = yo;
  }
  if (WB16) {
    ushort4 u;
    u.x = f2bf(y[0]); u.y = f2bf(y[1]); u.z = f2bf(y[2]); u.w = f2bf(y[3]);
    *(ushort4*)(ob + (size_t)row * 1024 + t * 4) = u;
  }
}

// ---------------- host orchestration ----------------
extern "C" void kernel_launch(void* const* d_in, const int* in_sizes, int n_in,
                              void* d_out, int out_size, void* d_ws, size_t ws_size,
                              hipStream_t stream) {
  const float* dec_inp = (const float*)d_in[0];
  const float* r_in = (const float*)d_in[1];
  const float* rwb = (const float*)d_in[2];
  const float* rrb = (const float*)d_in[3];
  const float* qkv_w = (const float*)d_in[4];
  const float* rnet_w = (const float*)d_in[5];
  const float* o_w = (const float*)d_in[6];
  const float* ln_attn_g = (const float*)d_in[7];
  const float* ln_attn_b = (const float*)d_in[8];
  const float* w1 = (const float*)d_in[9];
  const float* b1 = (const float*)d_in[10];
  const float* w2 = (const float*)d_in[11];
  const float* b2 = (const float*)d_in[12];
  const float* ln_ff_g = (const float*)d_in[13];
  const float* ln_ff_b = (const float*)d_in[14];
  float* out = (float*)d_out;

  char* ws = (char*)d_ws;
  size_t off = 0;
  auto alloc = [&](size_t bytes) {
    char* p = ws + off;
    off += (bytes + 255) & ~(size_t)255;
    return p;
  };
  const int ROWS = QL * 2;
  ushort* qkvw_b = (ushort*)alloc((size_t)3072 * 1024 * 2);
  ushort* rnetw_b = (ushort*)alloc((size_t)1024 * 1024 * 2);
  ushort* ow_b = (ushort*)alloc((size_t)1024 * 1024 * 2);
  ushort* w1_b = (ushort*)alloc((size_t)4096 * 1024 * 2);
  ushort* w2_b = (ushort*)alloc((size_t)1024 * 4096 * 2);
  ushort* x_b = (ushort*)alloc((size_t)ROWS * 1024 * 2);
  ushort* r_b = (ushort*)alloc((size_t)QL * 1024 * 2);
  ushort* Qw = (ushort*)alloc((size_t)32 * QL * 64 * 2);
  ushort* Qr = (ushort*)alloc((size_t)32 * QL * 64 * 2);
  ushort* Kb = (ushort*)alloc((size_t)32 * QL * 64 * 2);
  ushort* Vt = (ushort*)alloc((size_t)32 * 64 * QL * 2);
  ushort* rk = (ushort*)alloc((size_t)16 * QL * 64 * 2);
  ushort* avec = (ushort*)alloc((size_t)ROWS * 1024 * 2);
  ushort* p0 = (ushort*)alloc((size_t)ROWS * 1024 * 2);
  ushort* p1 = (ushort*)alloc((size_t)ROWS * 1024 * 2);
  ushort* x1b = (ushort*)alloc((size_t)ROWS * 1024 * 2);
  ushort* hidden = (ushort*)alloc((size_t)ROWS * 4096 * 2);
  ushort* q0 = (ushort*)alloc((size_t)ROWS * 1024 * 2);
  ushort* q1 = (ushort*)alloc((size_t)ROWS * 1024 * 2);

  // critical-path conversions: qkv_w, rnet_w, dec_inp, r
  CvtArgs ca;
  {
    int n4[4] = {3072 * 1024 / 4, 1024 * 1024 / 4, ROWS * 1024 / 4, QL * 1024 / 4};
    const float* srcs[4] = {qkv_w, rnet_w, dec_inp, r_in};
    ushort* dsts[4] = {qkvw_b, rnetw_b, x_b, r_b};
    int cum = 0;
    for (int i = 0; i < 4; i++) {
      ca.src[i] = srcs[i];
      ca.dst[i] = dsts[i];
      cum += n4[i];
      ca.end[i] = cum;
    }
    cvt_all_k<<<2048, 256, 0, stream>>>(ca, cum);
  }

  // fat dispatch: QKV proj + rk proj + deferred cvt of o_w/w1/w2
  Cvt3 cv;
  int cvt_total4;
  {
    int n4[3] = {1024 * 1024 / 4, 4096 * 1024 / 4, 1024 * 4096 / 4};
    const float* srcs[3] = {o_w, w1, w2};
    ushort* dsts[3] = {ow_b, w1_b, w2_b};
    int cum = 0;
    for (int i = 0; i < 3; i++) {
      cv.src[i] = srcs[i];
      cv.dst[i] = dsts[i];
      cum += n4[i];
      cv.end[i] = cum;
    }
    cvt_total4 = cum;
  }
  fat_qkv_rk_cvt<<<1792, 256, 0, stream>>>(x_b, qkvw_b, r_b, rnetw_b, Qw, Qr, Kb, Vt, rk,
                                           rwb, rrb, cv, cvt_total4);

  flash_attn<<<dim3(16, 32), 256, 0, stream>>>(Qw, Qr, Kb, Vt, rk, avec);
  // o-proj split-K=2 (K=512 each), bf16 partials p0/p1
  gemm_nt64sk<0><<<dim3(1024 / 64, ROWS / 128, 2), 256, 0, stream>>>(
      avec, ow_b, ROWS, 1024, 1024, 512, p0, p1, nullptr);
  // post-LN 1: residual dec_inp (f32) + p0 + p1 -> x1b (bf16 only)
  ln_res3<false, true, false><<<ROWS, 256, 0, stream>>>(
      dec_inp, p0, p1, ln_attn_g, ln_attn_b, nullptr, x1b);
  gemm_ffn1<<<dim3(4096 / 128, ROWS / 128), 256, 0, stream>>>(
      x1b, w1_b, ROWS, 4096, 1024, hidden, b1);
  // FFN2 split-K=2 (K=2048 each), bias folded into z==0 partial
  gemm_nt64sk<1><<<dim3(1024 / 64, ROWS / 128, 2), 256, 0, stream>>>(
      hidden, w2_b, ROWS, 1024, 4096, 2048, q0, q1, b2);
  // post-LN 2: residual x1b (bf16) + q0 + q1 -> out (f32)
  ln_res3<true, false, true><<<ROWS, 256, 0, stream>>>(
      x1b, q0, q1, ln_ff_g, ln_ff_b, out, nullptr);
}